// Round 2
// baseline (5116.088 us; speedup 1.0000x reference)
//
#include <hip/hip_runtime.h>

// ---------------------------------------------------------------------------
// TemporalCfCEncoder: T=128, N=256, D=256, H=4 heads (hd=64), L=3 layers.
//  - token block (LN/QKV/attn/out/LN/MLP) batched over T*N rows, bf16 MFMA GEMMs
//  - CfC scan: x-part precomputed as GEMM P=[f1|f2|gate] pre-activations (bf16);
//    h-part per-step, one WG per sequence n (sequences independent -> no
//    inter-WG sync). Scan weights packed bf16 k-interleaved for coalesced loads.
//  - Workspace aliasing: qkv / ff1-out / P share one 50MB region (disjoint
//    live ranges). Total ws use ~138 MB.
// ---------------------------------------------------------------------------

#define T_DIM 128
#define N_DIM 256
#define D_DIM 256
#define H_DIM 4
#define HD_DIM 64
#define L_DIM 3
#define TN (T_DIM * N_DIM)

typedef __bf16 bf16x8 __attribute__((ext_vector_type(8)));
typedef __bf16 bf16x4 __attribute__((ext_vector_type(4)));
typedef float f32x4 __attribute__((ext_vector_type(4)));

__device__ inline float wave_reduce_sum(float v) {
#pragma unroll
  for (int off = 32; off > 0; off >>= 1) v += __shfl_xor(v, off);
  return v;
}

// ---------------- LN: one wave per row of 256, f32 in -> bf16 out ----------
__global__ __launch_bounds__(256) void ln_kernel(const float* __restrict__ x,
                                                 const float* __restrict__ sc,
                                                 const float* __restrict__ bi,
                                                 __bf16* __restrict__ y) {
  const int wid = threadIdx.x >> 6;
  const int lane = threadIdx.x & 63;
  const size_t row = (size_t)blockIdx.x * 4 + wid;
  const float4 xv = *(const float4*)(x + row * D_DIM + lane * 4);
  float s = xv.x + xv.y + xv.z + xv.w;
  float ss = xv.x * xv.x + xv.y * xv.y + xv.z * xv.z + xv.w * xv.w;
  s = wave_reduce_sum(s);
  ss = wave_reduce_sum(ss);
  const float mean = s * (1.f / D_DIM);
  const float var = ss * (1.f / D_DIM) - mean * mean;
  const float r = rsqrtf(var + 1e-5f);
  const float4 scv = *(const float4*)(sc + lane * 4);
  const float4 biv = *(const float4*)(bi + lane * 4);
  bf16x4 ov;
  ov[0] = (__bf16)((xv.x - mean) * r * scv.x + biv.x);
  ov[1] = (__bf16)((xv.y - mean) * r * scv.y + biv.y);
  ov[2] = (__bf16)((xv.z - mean) * r * scv.z + biv.z);
  ov[3] = (__bf16)((xv.w - mean) * r * scv.w + biv.w);
  *(bf16x4*)(y + row * D_DIM + lane * 4) = ov;
}

// ---------------- GEMM: out = A[M,K] @ W[Nout,K]^T + bias (+epilogue) ------
// EPI: 0 = bias only, 1 = bias + residual R[M,Nout] (f32), 2 = bias + SiLU
// OBF: 1 -> bf16 out, 0 -> f32 out
// WG = 256 thr = 4 waves; each wave does a 16x64 tile (4 n-tiles of 16x16).
template <int EPI, int OBF>
__global__ __launch_bounds__(256) void gemm_kernel(const __bf16* __restrict__ A,
                                                   const __bf16* __restrict__ W,
                                                   const float* __restrict__ bias,
                                                   const float* __restrict__ R,
                                                   void* __restrict__ outv,
                                                   int M, int Nout, int K) {
  const int w = threadIdx.x >> 6;
  const int l = threadIdx.x & 63;
  const int lr = l & 15;   // A row / B col within 16-tile
  const int kg = l >> 4;   // k-group (8 elems each)
  const int m0 = blockIdx.x * 64 + w * 16;
  const int n0 = blockIdx.y * 64;
  const __bf16* Arow = A + (size_t)(m0 + lr) * K + kg * 8;
  f32x4 acc[4] = {};
  for (int k0 = 0; k0 < K; k0 += 32) {
    bf16x8 a = *(const bf16x8*)(Arow + k0);
#pragma unroll
    for (int nt = 0; nt < 4; ++nt) {
      bf16x8 b = *(const bf16x8*)(W + (size_t)(n0 + nt * 16 + lr) * K + kg * 8 + k0);
      acc[nt] = __builtin_amdgcn_mfma_f32_16x16x32_bf16(a, b, acc[nt], 0, 0, 0);
    }
  }
#pragma unroll
  for (int nt = 0; nt < 4; ++nt) {
    const int col = n0 + nt * 16 + lr;
    const float bv = bias[col];
#pragma unroll
    for (int j = 0; j < 4; ++j) {
      const int row = m0 + kg * 4 + j;
      float v = acc[nt][j] + bv;
      if (EPI == 1) v += R[(size_t)row * Nout + col];
      if (EPI == 2) v = v * (1.f / (1.f + __expf(-v)));
      const size_t oi = (size_t)row * Nout + col;
      if (OBF)
        ((__bf16*)outv)[oi] = (__bf16)v;
      else
        ((float*)outv)[oi] = v;
    }
  }
}

// ---------------- Attention: one WG per (t, head); thread = query row ------
// K/V staged in LDS as bf16 (64 KB total). Per-kk reads are wave-uniform
// (broadcast, conflict-free).
__global__ __launch_bounds__(256) void attn_kernel(const __bf16* __restrict__ qkv,
                                                   __bf16* __restrict__ o) {
  const int t = blockIdx.x, h = blockIdx.y, tid = threadIdx.x;
  __shared__ __bf16 k_lds[256][64];
  __shared__ __bf16 v_lds[256][64];
  const __bf16* base = qkv + ((size_t)(t * N_DIM + tid)) * 768 + h * HD_DIM;
  float q[64];
#pragma unroll
  for (int c8 = 0; c8 < 64; c8 += 8) {
    bf16x8 qv = *(const bf16x8*)(base + c8);
    bf16x8 kv = *(const bf16x8*)(base + 256 + c8);
    bf16x8 vv = *(const bf16x8*)(base + 512 + c8);
    *(bf16x8*)&k_lds[tid][c8] = kv;
    *(bf16x8*)&v_lds[tid][c8] = vv;
#pragma unroll
    for (int i = 0; i < 8; ++i) q[c8 + i] = (float)qv[i] * 0.125f;  // 1/sqrt(64)
  }
  __syncthreads();
  float m = -3.0e38f, lsum = 0.f;
  float oa[64];
#pragma unroll
  for (int c = 0; c < 64; ++c) oa[c] = 0.f;
  for (int kk = 0; kk < 256; ++kk) {
    float s = 0.f;
#pragma unroll
    for (int c8 = 0; c8 < 64; c8 += 8) {
      bf16x8 kv = *(const bf16x8*)&k_lds[kk][c8];
#pragma unroll
      for (int i = 0; i < 8; ++i) s += q[c8 + i] * (float)kv[i];
    }
    const float nm = fmaxf(m, s);
    const float scale = __expf(m - nm);
    const float p = __expf(s - nm);
    lsum = lsum * scale + p;
#pragma unroll
    for (int c8 = 0; c8 < 64; c8 += 8) {
      bf16x8 vv = *(const bf16x8*)&v_lds[kk][c8];
#pragma unroll
      for (int i = 0; i < 8; ++i) oa[c8 + i] = oa[c8 + i] * scale + p * (float)vv[i];
    }
    m = nm;
  }
  const float inv = 1.f / lsum;
  __bf16* orow = o + ((size_t)(t * N_DIM + tid)) * D_DIM + h * HD_DIM;
#pragma unroll
  for (int c8 = 0; c8 < 64; c8 += 8) {
    bf16x8 ov;
#pragma unroll
    for (int i = 0; i < 8; ++i) ov[i] = (__bf16)(oa[c8 + i] * inv);
    *(bf16x8*)(orow + c8) = ov;
  }
}

// ---------------- CfC scan: one WG per sequence n; thread j owns h[j] ------
// P[t*N+n][0:256]=f1 pre, [256:512]=f2 pre, [512:768]=gate pre (biases folded),
// stored bf16. Whp packed: [k0/8][768][8] bf16 -> contiguous 16B per lane.
__global__ __launch_bounds__(256) void scan_kernel(const __bf16* __restrict__ P,
                                                   const __bf16* __restrict__ Whp,
                                                   const float* __restrict__ logtau,
                                                   const float* __restrict__ st,
                                                   const float* __restrict__ addsrc,
                                                   float* __restrict__ out) {
  const int n = blockIdx.x, j = threadIdx.x;
  __shared__ float h_lds[256];
  __shared__ float st_s[T_DIM];
  if (j < T_DIM) st_s[j] = st[j];
  h_lds[j] = 0.f;
  const float tau = __expf(logtau[j]);
  __syncthreads();
  for (int t = 0; t < T_DIM; ++t) {
    const float dt = (t == 0) ? st_s[0] : (st_s[t] - st_s[t - 1]);
    const __bf16* Prow = P + ((size_t)(t * N_DIM + n)) * 768;
    float a1 = (float)Prow[j];
    float a2 = (float)Prow[256 + j];
    float a3 = (float)Prow[512 + j] - tau * dt;
#pragma unroll 4
    for (int k0 = 0; k0 < 256; k0 += 8) {
      const __bf16* wp = Whp + (size_t)(k0 >> 3) * 6144 + j * 8;
      bf16x8 w1 = *(const bf16x8*)(wp);
      bf16x8 w2 = *(const bf16x8*)(wp + 2048);
      bf16x8 w3 = *(const bf16x8*)(wp + 4096);
#pragma unroll
      for (int i = 0; i < 8; ++i) {
        const float hk = h_lds[k0 + i];
        a1 += hk * (float)w1[i];
        a2 += hk * (float)w2[i];
        a3 += hk * (float)w3[i];
      }
    }
    const float f1 = tanhf(a1);
    const float f2 = tanhf(a2);
    const float g = 1.f / (1.f + __expf(-a3));
    const float hn = g * f1 + (1.f - g) * f2;
    __syncthreads();
    h_lds[j] = hn;
    const size_t oi = ((size_t)(t * N_DIM + n)) * D_DIM + j;
    out[oi] = addsrc ? (hn + addsrc[oi]) : hn;
    __syncthreads();
  }
}

// ---------------- prep kernels ---------------------------------------------
__global__ void cvt_kernel(const float* __restrict__ src, __bf16* __restrict__ dst, int n) {
  const int i = blockIdx.x * 256 + threadIdx.x;
  if (i < n) dst[i] = (__bf16)src[i];
}

__global__ void pack_cell_kernel(const float* __restrict__ w1, const float* __restrict__ w2,
                                 const float* __restrict__ wt, __bf16* __restrict__ Wx,
                                 __bf16* __restrict__ Whp) {
  const int idx = blockIdx.x * 256 + threadIdx.x;  // over 3*768*256
  if (idx >= 3 * 768 * 256) return;
  const int l = idx / (768 * 256);
  const int r2 = idx - l * (768 * 256);
  const int jj = r2 >> 8;  // 0..767
  const int c = r2 & 255;
  const int m = jj >> 8;  // which matrix
  const int r = jj & 255;
  const float* src = (m == 0 ? w1 : (m == 1 ? w2 : wt)) + ((size_t)l * 256 + r) * 512;
  Wx[(size_t)l * (768 * 256) + (size_t)jj * 256 + c] = (__bf16)src[c];
  Whp[(size_t)l * (768 * 256) + (size_t)(c >> 3) * 6144 + jj * 8 + (c & 7)] =
      (__bf16)src[256 + c];
}

__global__ void bias_pack_kernel(const float* __restrict__ b1, const float* __restrict__ b2,
                                 const float* __restrict__ bt, const float* __restrict__ ff2b,
                                 const float* __restrict__ rw, const float* __restrict__ rb,
                                 const float* __restrict__ rn, float* __restrict__ bias768,
                                 float* __restrict__ ff2bias) {
  const int idx = blockIdx.x * 256 + threadIdx.x;
  if (idx < 3 * 768) {
    const int l = idx / 768, jj = idx % 768, m = jj >> 8, r = jj & 255;
    const float* s = (m == 0 ? b1 : (m == 1 ? b2 : bt));
    bias768[idx] = s[l * 256 + r];
  }
  if (idx < 256) ff2bias[idx] = ff2b[idx] + rw[idx] * rn[0] + rb[idx];
}

// ---------------------------------------------------------------------------
extern "C" void kernel_launch(void* const* d_in, const int* in_sizes, int n_in,
                              void* d_out, int out_size, void* d_ws, size_t ws_size,
                              hipStream_t stream) {
  (void)in_sizes; (void)n_in; (void)out_size; (void)ws_size;
  const float* spatial = (const float*)d_in[0];
  const float* re_norm = (const float*)d_in[1];
  const float* sensor_time = (const float*)d_in[2];
  const float* re_proj_w = (const float*)d_in[3];
  const float* re_proj_b = (const float*)d_in[4];
  const float* n1s = (const float*)d_in[5];
  const float* n1b = (const float*)d_in[6];
  const float* in_w = (const float*)d_in[7];
  const float* in_b = (const float*)d_in[8];
  const float* out_w = (const float*)d_in[9];
  const float* out_b = (const float*)d_in[10];
  const float* n2s = (const float*)d_in[11];
  const float* n2b = (const float*)d_in[12];
  const float* ff1_w = (const float*)d_in[13];
  const float* ff1_b = (const float*)d_in[14];
  const float* ff2_w = (const float*)d_in[15];
  const float* ff2_b = (const float*)d_in[16];
  const float* c1w = (const float*)d_in[17];
  const float* c1b = (const float*)d_in[18];
  const float* c2w = (const float*)d_in[19];
  const float* c2b = (const float*)d_in[20];
  const float* clt = (const float*)d_in[21];
  const float* ctw = (const float*)d_in[22];
  const float* ctb = (const float*)d_in[23];

  char* ws = (char*)d_ws;
  size_t off = 0;
  auto alloc = [&](size_t b) {
    char* p = ws + off;
    off = (off + b + 255) & ~(size_t)255;
    return p;
  };
  // persistent-per-layer buffers
  float* seq = (float*)alloc((size_t)TN * D_DIM * 4);      // 33.5 MB
  float* xb = (float*)alloc((size_t)TN * D_DIM * 4);       // 33.5 MB
  __bf16* yb = (__bf16*)alloc((size_t)TN * D_DIM * 2);     // 16.8 MB
  // big aliased region: qkv (bf16 TN*768) / ff1-out (bf16 TN*512) / P (bf16 TN*768)
  char* big = (char*)alloc((size_t)TN * 768 * 2);          // 50.3 MB
  __bf16* qkvb = (__bf16*)big;
  __bf16* gb = (__bf16*)big;
  __bf16* Pb = (__bf16*)big;
  // weights (~3.4 MB)
  __bf16* w_in = (__bf16*)alloc(768 * 256 * 2);
  __bf16* w_out = (__bf16*)alloc(256 * 256 * 2);
  __bf16* w_f1 = (__bf16*)alloc(512 * 256 * 2);
  __bf16* w_f2 = (__bf16*)alloc(256 * 512 * 2);
  __bf16* Wx = (__bf16*)alloc((size_t)3 * 768 * 256 * 2);
  __bf16* Whp = (__bf16*)alloc((size_t)3 * 768 * 256 * 2);
  float* b768 = (float*)alloc(3 * 768 * 4);
  float* f2bias = (float*)alloc(256 * 4);

  cvt_kernel<<<(768 * 256 + 255) / 256, 256, 0, stream>>>(in_w, w_in, 768 * 256);
  cvt_kernel<<<(256 * 256 + 255) / 256, 256, 0, stream>>>(out_w, w_out, 256 * 256);
  cvt_kernel<<<(512 * 256 + 255) / 256, 256, 0, stream>>>(ff1_w, w_f1, 512 * 256);
  cvt_kernel<<<(256 * 512 + 255) / 256, 256, 0, stream>>>(ff2_w, w_f2, 256 * 512);
  pack_cell_kernel<<<(3 * 768 * 256 + 255) / 256, 256, 0, stream>>>(c1w, c2w, ctw, Wx, Whp);
  bias_pack_kernel<<<9, 256, 0, stream>>>(c1b, c2b, ctb, ff2_b, re_proj_w, re_proj_b,
                                          re_norm, b768, f2bias);

  for (int l = 0; l < L_DIM; ++l) {
    const float* seq_in = (l == 0) ? spatial : seq;
    ln_kernel<<<TN / 4, 256, 0, stream>>>(seq_in, n1s, n1b, yb);
    gemm_kernel<0, 1><<<dim3(TN / 64, 768 / 64), 256, 0, stream>>>(yb, w_in, in_b, nullptr,
                                                                   qkvb, TN, 768, 256);
    attn_kernel<<<dim3(T_DIM, H_DIM), 256, 0, stream>>>(qkvb, yb);
    gemm_kernel<1, 0><<<dim3(TN / 64, 256 / 64), 256, 0, stream>>>(yb, w_out, out_b, seq_in,
                                                                   xb, TN, 256, 256);
    ln_kernel<<<TN / 4, 256, 0, stream>>>(xb, n2s, n2b, yb);
    gemm_kernel<2, 1><<<dim3(TN / 64, 512 / 64), 256, 0, stream>>>(yb, w_f1, ff1_b, nullptr,
                                                                   gb, TN, 512, 256);
    gemm_kernel<1, 1><<<dim3(TN / 64, 256 / 64), 256, 0, stream>>>(gb, w_f2, f2bias, xb, yb,
                                                                   TN, 256, 512);
    gemm_kernel<0, 1><<<dim3(TN / 64, 768 / 64), 256, 0, stream>>>(
        yb, Wx + (size_t)l * 768 * 256, b768 + l * 768, nullptr, Pb, TN, 768, 256);
    float* outp = (l == 2) ? (float*)d_out : seq;
    const float* addp = (l == 0) ? nullptr : seq;
    scan_kernel<<<N_DIM, 256, 0, stream>>>(Pb, Whp + (size_t)l * 768 * 256, clt + l * 256,
                                           sensor_time, addp, outp);
  }
}

// Round 3
// 3371.252 us; speedup vs baseline: 1.5176x; 1.5176x over previous
//
#include <hip/hip_runtime.h>

// ---------------------------------------------------------------------------
// TemporalCfCEncoder: T=128, N=256, D=256, H=4 heads (hd=64), L=3 layers.
//  - token block (LN/QKV/attn/out/LN/MLP) batched over T*N rows, bf16 MFMA GEMMs
//  - CfC scan: x-part precomputed as GEMM P=[f1|f2|gate] (bf16). h-part:
//    MFMA scan, 16 sequences per WG, Wh (768x256 bf16) fully resident in
//    VGPRs (48 frags/lane), h carried bf16 in LDS, 2 barriers/step.
// ---------------------------------------------------------------------------

#define T_DIM 128
#define N_DIM 256
#define D_DIM 256
#define H_DIM 4
#define HD_DIM 64
#define L_DIM 3
#define TN (T_DIM * N_DIM)

typedef __bf16 bf16x8 __attribute__((ext_vector_type(8)));
typedef __bf16 bf16x4 __attribute__((ext_vector_type(4)));
typedef float f32x4 __attribute__((ext_vector_type(4)));

__device__ inline float wave_reduce_sum(float v) {
#pragma unroll
  for (int off = 32; off > 0; off >>= 1) v += __shfl_xor(v, off);
  return v;
}

// ---------------- LN: one wave per row of 256, f32 in -> bf16 out ----------
__global__ __launch_bounds__(256) void ln_kernel(const float* __restrict__ x,
                                                 const float* __restrict__ sc,
                                                 const float* __restrict__ bi,
                                                 __bf16* __restrict__ y) {
  const int wid = threadIdx.x >> 6;
  const int lane = threadIdx.x & 63;
  const size_t row = (size_t)blockIdx.x * 4 + wid;
  const float4 xv = *(const float4*)(x + row * D_DIM + lane * 4);
  float s = xv.x + xv.y + xv.z + xv.w;
  float ss = xv.x * xv.x + xv.y * xv.y + xv.z * xv.z + xv.w * xv.w;
  s = wave_reduce_sum(s);
  ss = wave_reduce_sum(ss);
  const float mean = s * (1.f / D_DIM);
  const float var = ss * (1.f / D_DIM) - mean * mean;
  const float r = rsqrtf(var + 1e-5f);
  const float4 scv = *(const float4*)(sc + lane * 4);
  const float4 biv = *(const float4*)(bi + lane * 4);
  bf16x4 ov;
  ov[0] = (__bf16)((xv.x - mean) * r * scv.x + biv.x);
  ov[1] = (__bf16)((xv.y - mean) * r * scv.y + biv.y);
  ov[2] = (__bf16)((xv.z - mean) * r * scv.z + biv.z);
  ov[3] = (__bf16)((xv.w - mean) * r * scv.w + biv.w);
  *(bf16x4*)(y + row * D_DIM + lane * 4) = ov;
}

// ---------------- GEMM: out = A[M,K] @ W[Nout,K]^T + bias (+epilogue) ------
template <int EPI, int OBF>
__global__ __launch_bounds__(256) void gemm_kernel(const __bf16* __restrict__ A,
                                                   const __bf16* __restrict__ W,
                                                   const float* __restrict__ bias,
                                                   const float* __restrict__ R,
                                                   void* __restrict__ outv,
                                                   int M, int Nout, int K) {
  const int w = threadIdx.x >> 6;
  const int l = threadIdx.x & 63;
  const int lr = l & 15;   // A row / B col within 16-tile
  const int kg = l >> 4;   // k-group (8 elems each)
  const int m0 = blockIdx.x * 64 + w * 16;
  const int n0 = blockIdx.y * 64;
  const __bf16* Arow = A + (size_t)(m0 + lr) * K + kg * 8;
  f32x4 acc[4] = {};
  for (int k0 = 0; k0 < K; k0 += 32) {
    bf16x8 a = *(const bf16x8*)(Arow + k0);
#pragma unroll
    for (int nt = 0; nt < 4; ++nt) {
      bf16x8 b = *(const bf16x8*)(W + (size_t)(n0 + nt * 16 + lr) * K + kg * 8 + k0);
      acc[nt] = __builtin_amdgcn_mfma_f32_16x16x32_bf16(a, b, acc[nt], 0, 0, 0);
    }
  }
#pragma unroll
  for (int nt = 0; nt < 4; ++nt) {
    const int col = n0 + nt * 16 + lr;
    const float bv = bias[col];
#pragma unroll
    for (int j = 0; j < 4; ++j) {
      const int row = m0 + kg * 4 + j;
      float v = acc[nt][j] + bv;
      if (EPI == 1) v += R[(size_t)row * Nout + col];
      if (EPI == 2) v = v * (1.f / (1.f + __expf(-v)));
      const size_t oi = (size_t)row * Nout + col;
      if (OBF)
        ((__bf16*)outv)[oi] = (__bf16)v;
      else
        ((float*)outv)[oi] = v;
    }
  }
}

// ---------------- Attention: one WG per (t, head); thread = query row ------
__global__ __launch_bounds__(256) void attn_kernel(const __bf16* __restrict__ qkv,
                                                   __bf16* __restrict__ o) {
  const int t = blockIdx.x, h = blockIdx.y, tid = threadIdx.x;
  __shared__ __bf16 k_lds[256][64];
  __shared__ __bf16 v_lds[256][64];
  const __bf16* base = qkv + ((size_t)(t * N_DIM + tid)) * 768 + h * HD_DIM;
  float q[64];
#pragma unroll
  for (int c8 = 0; c8 < 64; c8 += 8) {
    bf16x8 qv = *(const bf16x8*)(base + c8);
    bf16x8 kv = *(const bf16x8*)(base + 256 + c8);
    bf16x8 vv = *(const bf16x8*)(base + 512 + c8);
    *(bf16x8*)&k_lds[tid][c8] = kv;
    *(bf16x8*)&v_lds[tid][c8] = vv;
#pragma unroll
    for (int i = 0; i < 8; ++i) q[c8 + i] = (float)qv[i] * 0.125f;  // 1/sqrt(64)
  }
  __syncthreads();
  float m = -3.0e38f, lsum = 0.f;
  float oa[64];
#pragma unroll
  for (int c = 0; c < 64; ++c) oa[c] = 0.f;
  for (int kk = 0; kk < 256; ++kk) {
    float s = 0.f;
#pragma unroll
    for (int c8 = 0; c8 < 64; c8 += 8) {
      bf16x8 kv = *(const bf16x8*)&k_lds[kk][c8];
#pragma unroll
      for (int i = 0; i < 8; ++i) s += q[c8 + i] * (float)kv[i];
    }
    const float nm = fmaxf(m, s);
    const float scale = __expf(m - nm);
    const float p = __expf(s - nm);
    lsum = lsum * scale + p;
#pragma unroll
    for (int c8 = 0; c8 < 64; c8 += 8) {
      bf16x8 vv = *(const bf16x8*)&v_lds[kk][c8];
#pragma unroll
      for (int i = 0; i < 8; ++i) oa[c8 + i] = oa[c8 + i] * scale + p * (float)vv[i];
    }
    m = nm;
  }
  const float inv = 1.f / lsum;
  __bf16* orow = o + ((size_t)(t * N_DIM + tid)) * D_DIM + h * HD_DIM;
#pragma unroll
  for (int c8 = 0; c8 < 64; c8 += 8) {
    bf16x8 ov;
#pragma unroll
    for (int i = 0; i < 8; ++i) ov[i] = (__bf16)(oa[c8 + i] * inv);
    *(bf16x8*)(orow + c8) = ov;
  }
}

// ---------------- CfC scan (MFMA): 16 sequences per WG, Wh in VGPRs --------
// P[t*N+n][0:256|256:512|512:768] bf16 pre-activations (biases folded).
// Wh row-major [768][256] bf16. 8 waves; wave w owns output cols w*96..+95.
__global__ __launch_bounds__(512) void scan_mfma(const __bf16* __restrict__ P,
                                                 const __bf16* __restrict__ Wh,
                                                 const float* __restrict__ logtau,
                                                 const float* __restrict__ st,
                                                 const float* __restrict__ addsrc,
                                                 float* __restrict__ out) {
  const int tid = threadIdx.x;
  const int w = tid >> 6, l = tid & 63;
  const int lr = l & 15, kg = l >> 4;
  const int n0 = blockIdx.x * 16;

  __shared__ float acc_lds[16][772];   // +4 pad -> 2-way banks only
  __shared__ __bf16 h_lds[16][264];    // +8 pad, 528B row stride (16B-aligned)
  __shared__ float dts[T_DIM];

  if (tid < T_DIM) dts[tid] = (tid == 0) ? st[0] : st[tid] - st[tid - 1];

  // combine-phase ownership: thread -> (sequence s, h-dims kb..kb+7)
  const int s = tid >> 5;
  const int kb = (tid & 31) << 3;
  float tau8[8];
#pragma unroll
  for (int i = 0; i < 8; ++i) tau8[i] = __expf(logtau[kb + i]);
  {
    bf16x8 z = {};
    *(bf16x8*)&h_lds[s][kb] = z;  // h0 = 0 (covers all read locations)
  }

  // preload Wh fragments: wave w cols [w*96 .. w*96+95], 6 n-tiles x 8 k-tiles
  bf16x8 wreg[6][8];
  {
    const __bf16* wb = Wh + (size_t)(w * 96 + lr) * 256 + kg * 8;
#pragma unroll
    for (int nt = 0; nt < 6; ++nt)
#pragma unroll
      for (int kt = 0; kt < 8; ++kt)
        wreg[nt][kt] = *(const bf16x8*)(wb + (size_t)nt * 16 * 256 + kt * 32);
  }
  __syncthreads();

  const __bf16* Pp = P + (size_t)(n0 + s) * 768 + kb;
  float* op = out + (size_t)(n0 + s) * D_DIM + kb;
  const float* ap = addsrc ? addsrc + (size_t)(n0 + s) * D_DIM + kb : nullptr;
  const char* hbase = (const char*)&h_lds[0][0] + lr * 528 + kg * 16;

  for (int t = 0; t < T_DIM; ++t) {
    // prefetch this step's P (waits land after MFMA phase)
    const bf16x8 p1 = *(const bf16x8*)(Pp);
    const bf16x8 p2 = *(const bf16x8*)(Pp + 256);
    const bf16x8 p3 = *(const bf16x8*)(Pp + 512);
    Pp += (size_t)N_DIM * 768;

    // MFMA phase: acc[16 seq][96 cols slice] += h @ Wh^T
    f32x4 acc[6] = {};
#pragma unroll
    for (int kt = 0; kt < 8; ++kt) {
      const bf16x8 a = *(const bf16x8*)(hbase + kt * 64);
#pragma unroll
      for (int nt = 0; nt < 6; ++nt)
        acc[nt] = __builtin_amdgcn_mfma_f32_16x16x32_bf16(a, wreg[nt][kt], acc[nt], 0, 0, 0);
    }
#pragma unroll
    for (int nt = 0; nt < 6; ++nt)
#pragma unroll
      for (int j = 0; j < 4; ++j)
        acc_lds[kg * 4 + j][w * 96 + nt * 16 + lr] = acc[nt][j];
    __syncthreads();

    // combine phase: h_new = sig(gpre)*tanh(a1) + (1-sig)*tanh(a2)
    const float dt = dts[t];
    const float4 r10 = *(const float4*)&acc_lds[s][kb];
    const float4 r11 = *(const float4*)&acc_lds[s][kb + 4];
    const float4 r20 = *(const float4*)&acc_lds[s][256 + kb];
    const float4 r21 = *(const float4*)&acc_lds[s][256 + kb + 4];
    const float4 r30 = *(const float4*)&acc_lds[s][512 + kb];
    const float4 r31 = *(const float4*)&acc_lds[s][512 + kb + 4];
    float a1v[8] = {r10.x, r10.y, r10.z, r10.w, r11.x, r11.y, r11.z, r11.w};
    float a2v[8] = {r20.x, r20.y, r20.z, r20.w, r21.x, r21.y, r21.z, r21.w};
    float a3v[8] = {r30.x, r30.y, r30.z, r30.w, r31.x, r31.y, r31.z, r31.w};
    float hv[8];
    bf16x8 hb;
#pragma unroll
    for (int i = 0; i < 8; ++i) {
      const float a1 = a1v[i] + (float)p1[i];
      const float a2 = a2v[i] + (float)p2[i];
      const float a3 = a3v[i] + (float)p3[i] - tau8[i] * dt;
      const float e1 = __expf(-2.f * fabsf(a1));
      const float f1 = copysignf((1.f - e1) / (1.f + e1), a1);
      const float e2 = __expf(-2.f * fabsf(a2));
      const float f2 = copysignf((1.f - e2) / (1.f + e2), a2);
      const float g = 1.f / (1.f + __expf(-a3));
      const float hn = g * f1 + (1.f - g) * f2;
      hv[i] = hn;
      hb[i] = (__bf16)hn;
    }
    *(bf16x8*)&h_lds[s][kb] = hb;
    float4 o0 = {hv[0], hv[1], hv[2], hv[3]};
    float4 o1 = {hv[4], hv[5], hv[6], hv[7]};
    if (ap) {
      const float4 q0 = *(const float4*)(ap);
      const float4 q1 = *(const float4*)(ap + 4);
      o0.x += q0.x; o0.y += q0.y; o0.z += q0.z; o0.w += q0.w;
      o1.x += q1.x; o1.y += q1.y; o1.z += q1.z; o1.w += q1.w;
      ap += (size_t)N_DIM * D_DIM;
    }
    *(float4*)(op) = o0;
    *(float4*)(op + 4) = o1;
    op += (size_t)N_DIM * D_DIM;
    __syncthreads();
  }
}

// ---------------- prep kernels ---------------------------------------------
__global__ void cvt_kernel(const float* __restrict__ src, __bf16* __restrict__ dst, int n) {
  const int i = blockIdx.x * 256 + threadIdx.x;
  if (i < n) dst[i] = (__bf16)src[i];
}

__global__ void pack_cell_kernel(const float* __restrict__ w1, const float* __restrict__ w2,
                                 const float* __restrict__ wt, __bf16* __restrict__ Wx,
                                 __bf16* __restrict__ Whb) {
  const int idx = blockIdx.x * 256 + threadIdx.x;  // over 3*768*256
  if (idx >= 3 * 768 * 256) return;
  const int l = idx / (768 * 256);
  const int r2 = idx - l * (768 * 256);
  const int jj = r2 >> 8;  // 0..767
  const int c = r2 & 255;
  const int m = jj >> 8;  // which matrix
  const int r = jj & 255;
  const float* src = (m == 0 ? w1 : (m == 1 ? w2 : wt)) + ((size_t)l * 256 + r) * 512;
  Wx[(size_t)l * (768 * 256) + (size_t)jj * 256 + c] = (__bf16)src[c];
  Whb[(size_t)l * (768 * 256) + (size_t)jj * 256 + c] = (__bf16)src[256 + c];
}

__global__ void bias_pack_kernel(const float* __restrict__ b1, const float* __restrict__ b2,
                                 const float* __restrict__ bt, const float* __restrict__ ff2b,
                                 const float* __restrict__ rw, const float* __restrict__ rb,
                                 const float* __restrict__ rn, float* __restrict__ bias768,
                                 float* __restrict__ ff2bias) {
  const int idx = blockIdx.x * 256 + threadIdx.x;
  if (idx < 3 * 768) {
    const int l = idx / 768, jj = idx % 768, m = jj >> 8, r = jj & 255;
    const float* s = (m == 0 ? b1 : (m == 1 ? b2 : bt));
    bias768[idx] = s[l * 256 + r];
  }
  if (idx < 256) ff2bias[idx] = ff2b[idx] + rw[idx] * rn[0] + rb[idx];
}

// ---------------------------------------------------------------------------
extern "C" void kernel_launch(void* const* d_in, const int* in_sizes, int n_in,
                              void* d_out, int out_size, void* d_ws, size_t ws_size,
                              hipStream_t stream) {
  (void)in_sizes; (void)n_in; (void)out_size; (void)ws_size;
  const float* spatial = (const float*)d_in[0];
  const float* re_norm = (const float*)d_in[1];
  const float* sensor_time = (const float*)d_in[2];
  const float* re_proj_w = (const float*)d_in[3];
  const float* re_proj_b = (const float*)d_in[4];
  const float* n1s = (const float*)d_in[5];
  const float* n1b = (const float*)d_in[6];
  const float* in_w = (const float*)d_in[7];
  const float* in_b = (const float*)d_in[8];
  const float* out_w = (const float*)d_in[9];
  const float* out_b = (const float*)d_in[10];
  const float* n2s = (const float*)d_in[11];
  const float* n2b = (const float*)d_in[12];
  const float* ff1_w = (const float*)d_in[13];
  const float* ff1_b = (const float*)d_in[14];
  const float* ff2_w = (const float*)d_in[15];
  const float* ff2_b = (const float*)d_in[16];
  const float* c1w = (const float*)d_in[17];
  const float* c1b = (const float*)d_in[18];
  const float* c2w = (const float*)d_in[19];
  const float* c2b = (const float*)d_in[20];
  const float* clt = (const float*)d_in[21];
  const float* ctw = (const float*)d_in[22];
  const float* ctb = (const float*)d_in[23];

  char* ws = (char*)d_ws;
  size_t off = 0;
  auto alloc = [&](size_t b) {
    char* p = ws + off;
    off = (off + b + 255) & ~(size_t)255;
    return p;
  };
  // persistent-per-layer buffers
  float* seq = (float*)alloc((size_t)TN * D_DIM * 4);      // 33.5 MB
  float* xb = (float*)alloc((size_t)TN * D_DIM * 4);       // 33.5 MB
  __bf16* yb = (__bf16*)alloc((size_t)TN * D_DIM * 2);     // 16.8 MB
  // big aliased region: qkv (bf16 TN*768) / ff1-out (bf16 TN*512) / P (bf16 TN*768)
  char* big = (char*)alloc((size_t)TN * 768 * 2);          // 50.3 MB
  __bf16* qkvb = (__bf16*)big;
  __bf16* gb = (__bf16*)big;
  __bf16* Pb = (__bf16*)big;
  // weights (~3.4 MB)
  __bf16* w_in = (__bf16*)alloc(768 * 256 * 2);
  __bf16* w_out = (__bf16*)alloc(256 * 256 * 2);
  __bf16* w_f1 = (__bf16*)alloc(512 * 256 * 2);
  __bf16* w_f2 = (__bf16*)alloc(256 * 512 * 2);
  __bf16* Wx = (__bf16*)alloc((size_t)3 * 768 * 256 * 2);
  __bf16* Whb = (__bf16*)alloc((size_t)3 * 768 * 256 * 2);
  float* b768 = (float*)alloc(3 * 768 * 4);
  float* f2bias = (float*)alloc(256 * 4);

  cvt_kernel<<<(768 * 256 + 255) / 256, 256, 0, stream>>>(in_w, w_in, 768 * 256);
  cvt_kernel<<<(256 * 256 + 255) / 256, 256, 0, stream>>>(out_w, w_out, 256 * 256);
  cvt_kernel<<<(512 * 256 + 255) / 256, 256, 0, stream>>>(ff1_w, w_f1, 512 * 256);
  cvt_kernel<<<(256 * 512 + 255) / 256, 256, 0, stream>>>(ff2_w, w_f2, 256 * 512);
  pack_cell_kernel<<<(3 * 768 * 256 + 255) / 256, 256, 0, stream>>>(c1w, c2w, ctw, Wx, Whb);
  bias_pack_kernel<<<9, 256, 0, stream>>>(c1b, c2b, ctb, ff2_b, re_proj_w, re_proj_b,
                                          re_norm, b768, f2bias);

  for (int l = 0; l < L_DIM; ++l) {
    const float* seq_in = (l == 0) ? spatial : seq;
    ln_kernel<<<TN / 4, 256, 0, stream>>>(seq_in, n1s, n1b, yb);
    gemm_kernel<0, 1><<<dim3(TN / 64, 768 / 64), 256, 0, stream>>>(yb, w_in, in_b, nullptr,
                                                                   qkvb, TN, 768, 256);
    attn_kernel<<<dim3(T_DIM, H_DIM), 256, 0, stream>>>(qkvb, yb);
    gemm_kernel<1, 0><<<dim3(TN / 64, 256 / 64), 256, 0, stream>>>(yb, w_out, out_b, seq_in,
                                                                   xb, TN, 256, 256);
    ln_kernel<<<TN / 4, 256, 0, stream>>>(xb, n2s, n2b, yb);
    gemm_kernel<2, 1><<<dim3(TN / 64, 512 / 64), 256, 0, stream>>>(yb, w_f1, ff1_b, nullptr,
                                                                   gb, TN, 512, 256);
    gemm_kernel<1, 1><<<dim3(TN / 64, 256 / 64), 256, 0, stream>>>(gb, w_f2, f2bias, xb, yb,
                                                                   TN, 256, 512);
    gemm_kernel<0, 1><<<dim3(TN / 64, 768 / 64), 256, 0, stream>>>(
        yb, Wx + (size_t)l * 768 * 256, b768 + l * 768, nullptr, Pb, TN, 768, 256);
    float* outp = (l == 2) ? (float*)d_out : seq;
    const float* addp = (l == 0) ? nullptr : seq;
    scan_mfma<<<16, 512, 0, stream>>>(Pb, Whb + (size_t)l * 768 * 256, clt + l * 256,
                                      sensor_time, addp, outp);
  }
}

// Round 4
// 2850.840 us; speedup vs baseline: 1.7946x; 1.1825x over previous
//
#include <hip/hip_runtime.h>

// ---------------------------------------------------------------------------
// TemporalCfCEncoder: T=128, N=256, D=256, H=4 heads (hd=64), L=3 layers.
//  - token block (LN/QKV/attn/out/LN/MLP) batched over T*N rows, bf16 MFMA GEMMs
//  - CfC scan: x-part precomputed as GEMM P=[f1|f2|gate] (bf16). h-part:
//    MFMA scan, SEQ=2 sequences per WG (128 WGs -> 128 CUs), Wh (768x256 bf16)
//    fully VGPR-resident, h carried bf16 in LDS, distance-2 P prefetch.
// ---------------------------------------------------------------------------

#define T_DIM 128
#define N_DIM 256
#define D_DIM 256
#define H_DIM 4
#define HD_DIM 64
#define L_DIM 3
#define TN (T_DIM * N_DIM)
#define SCAN_SEQ 2

typedef __bf16 bf16x8 __attribute__((ext_vector_type(8)));
typedef __bf16 bf16x4 __attribute__((ext_vector_type(4)));
typedef float f32x4 __attribute__((ext_vector_type(4)));

__device__ inline float wave_reduce_sum(float v) {
#pragma unroll
  for (int off = 32; off > 0; off >>= 1) v += __shfl_xor(v, off);
  return v;
}

__device__ inline float bf_to_f(unsigned short u) {
  return __uint_as_float((unsigned int)u << 16);
}

// ---------------- LN: one wave per row of 256, f32 in -> bf16 out ----------
__global__ __launch_bounds__(256) void ln_kernel(const float* __restrict__ x,
                                                 const float* __restrict__ sc,
                                                 const float* __restrict__ bi,
                                                 __bf16* __restrict__ y) {
  const int wid = threadIdx.x >> 6;
  const int lane = threadIdx.x & 63;
  const size_t row = (size_t)blockIdx.x * 4 + wid;
  const float4 xv = *(const float4*)(x + row * D_DIM + lane * 4);
  float s = xv.x + xv.y + xv.z + xv.w;
  float ss = xv.x * xv.x + xv.y * xv.y + xv.z * xv.z + xv.w * xv.w;
  s = wave_reduce_sum(s);
  ss = wave_reduce_sum(ss);
  const float mean = s * (1.f / D_DIM);
  const float var = ss * (1.f / D_DIM) - mean * mean;
  const float r = rsqrtf(var + 1e-5f);
  const float4 scv = *(const float4*)(sc + lane * 4);
  const float4 biv = *(const float4*)(bi + lane * 4);
  bf16x4 ov;
  ov[0] = (__bf16)((xv.x - mean) * r * scv.x + biv.x);
  ov[1] = (__bf16)((xv.y - mean) * r * scv.y + biv.y);
  ov[2] = (__bf16)((xv.z - mean) * r * scv.z + biv.z);
  ov[3] = (__bf16)((xv.w - mean) * r * scv.w + biv.w);
  *(bf16x4*)(y + row * D_DIM + lane * 4) = ov;
}

// ---------------- GEMM: out = A[M,K] @ W[Nout,K]^T + bias (+epilogue) ------
template <int EPI, int OBF>
__global__ __launch_bounds__(256) void gemm_kernel(const __bf16* __restrict__ A,
                                                   const __bf16* __restrict__ W,
                                                   const float* __restrict__ bias,
                                                   const float* __restrict__ R,
                                                   void* __restrict__ outv,
                                                   int M, int Nout, int K) {
  const int w = threadIdx.x >> 6;
  const int l = threadIdx.x & 63;
  const int lr = l & 15;   // A row / B col within 16-tile
  const int kg = l >> 4;   // k-group (8 elems each)
  const int m0 = blockIdx.x * 64 + w * 16;
  const int n0 = blockIdx.y * 64;
  const __bf16* Arow = A + (size_t)(m0 + lr) * K + kg * 8;
  f32x4 acc[4] = {};
  for (int k0 = 0; k0 < K; k0 += 32) {
    bf16x8 a = *(const bf16x8*)(Arow + k0);
#pragma unroll
    for (int nt = 0; nt < 4; ++nt) {
      bf16x8 b = *(const bf16x8*)(W + (size_t)(n0 + nt * 16 + lr) * K + kg * 8 + k0);
      acc[nt] = __builtin_amdgcn_mfma_f32_16x16x32_bf16(a, b, acc[nt], 0, 0, 0);
    }
  }
#pragma unroll
  for (int nt = 0; nt < 4; ++nt) {
    const int col = n0 + nt * 16 + lr;
    const float bv = bias[col];
#pragma unroll
    for (int j = 0; j < 4; ++j) {
      const int row = m0 + kg * 4 + j;
      float v = acc[nt][j] + bv;
      if (EPI == 1) v += R[(size_t)row * Nout + col];
      if (EPI == 2) v = v * (1.f / (1.f + __expf(-v)));
      const size_t oi = (size_t)row * Nout + col;
      if (OBF)
        ((__bf16*)outv)[oi] = (__bf16)v;
      else
        ((float*)outv)[oi] = v;
    }
  }
}

// ---------------- Attention: one WG per (t, head); thread = query row ------
__global__ __launch_bounds__(256) void attn_kernel(const __bf16* __restrict__ qkv,
                                                   __bf16* __restrict__ o) {
  const int t = blockIdx.x, h = blockIdx.y, tid = threadIdx.x;
  __shared__ __bf16 k_lds[256][64];
  __shared__ __bf16 v_lds[256][64];
  const __bf16* base = qkv + ((size_t)(t * N_DIM + tid)) * 768 + h * HD_DIM;
  float q[64];
#pragma unroll
  for (int c8 = 0; c8 < 64; c8 += 8) {
    bf16x8 qv = *(const bf16x8*)(base + c8);
    bf16x8 kv = *(const bf16x8*)(base + 256 + c8);
    bf16x8 vv = *(const bf16x8*)(base + 512 + c8);
    *(bf16x8*)&k_lds[tid][c8] = kv;
    *(bf16x8*)&v_lds[tid][c8] = vv;
#pragma unroll
    for (int i = 0; i < 8; ++i) q[c8 + i] = (float)qv[i] * 0.125f;  // 1/sqrt(64)
  }
  __syncthreads();
  float m = -3.0e38f, lsum = 0.f;
  float oa[64];
#pragma unroll
  for (int c = 0; c < 64; ++c) oa[c] = 0.f;
  for (int kk = 0; kk < 256; ++kk) {
    float s = 0.f;
#pragma unroll
    for (int c8 = 0; c8 < 64; c8 += 8) {
      bf16x8 kv = *(const bf16x8*)&k_lds[kk][c8];
#pragma unroll
      for (int i = 0; i < 8; ++i) s += q[c8 + i] * (float)kv[i];
    }
    const float nm = fmaxf(m, s);
    const float scale = __expf(m - nm);
    const float p = __expf(s - nm);
    lsum = lsum * scale + p;
#pragma unroll
    for (int c8 = 0; c8 < 64; c8 += 8) {
      bf16x8 vv = *(const bf16x8*)&v_lds[kk][c8];
#pragma unroll
      for (int i = 0; i < 8; ++i) oa[c8 + i] = oa[c8 + i] * scale + p * (float)vv[i];
    }
    m = nm;
  }
  const float inv = 1.f / lsum;
  __bf16* orow = o + ((size_t)(t * N_DIM + tid)) * D_DIM + h * HD_DIM;
#pragma unroll
  for (int c8 = 0; c8 < 64; c8 += 8) {
    bf16x8 ov;
#pragma unroll
    for (int i = 0; i < 8; ++i) ov[i] = (__bf16)(oa[c8 + i] * inv);
    *(bf16x8*)(orow + c8) = ov;
  }
}

// ---------------- CfC scan (MFMA): SEQ=2 sequences/WG, Wh in VGPRs ---------
// P[t*N+n][0:256|256:512|512:768] bf16 pre-activations (biases folded).
// Wh row-major [768][256] bf16. 8 waves; wave w owns output cols w*96..+95.
// h rows >= SEQ stay zero -> MFMA rows >= SEQ are zero (ignored).
__global__ __launch_bounds__(512) void scan_mfma(const __bf16* __restrict__ P,
                                                 const __bf16* __restrict__ Wh,
                                                 const float* __restrict__ logtau,
                                                 const float* __restrict__ st,
                                                 const float* __restrict__ addsrc,
                                                 float* __restrict__ out) {
  const int tid = threadIdx.x;
  const int w = tid >> 6, l = tid & 63;
  const int lr = l & 15, kg = l >> 4;
  const int n0 = blockIdx.x * SCAN_SEQ;

  __shared__ float acc_lds[SCAN_SEQ][772];
  __shared__ __bf16 h_lds[16][264];  // 528B row stride; rows >= SEQ stay 0
  __shared__ float dts[T_DIM];

  if (tid < T_DIM) dts[tid] = (tid == 0) ? st[0] : st[tid] - st[tid - 1];
  for (int i = tid; i < 16 * 33; i += 512) ((bf16x8*)h_lds)[i] = (bf16x8){};

  // preload Wh fragments: wave w cols [w*96 .. w*96+95], 6 n-tiles x 8 k-tiles
  bf16x8 wreg[6][8];
  {
    const __bf16* wb = Wh + (size_t)(w * 96 + lr) * 256 + kg * 8;
#pragma unroll
    for (int nt = 0; nt < 6; ++nt)
#pragma unroll
      for (int kt = 0; kt < 8; ++kt)
        wreg[nt][kt] = *(const bf16x8*)(wb + (size_t)nt * 16 * 256 + kt * 32);
  }
  __syncthreads();

  // combine-phase ownership: thread -> (sequence s, h-dim d)
  const int s = tid >> 8;    // 0..1
  const int d = tid & 255;   // 0..255
  const float tau = __expf(logtau[d]);
  const unsigned short* Pp = (const unsigned short*)P + (size_t)(n0 + s) * 768 + d;
  float* op = out + (size_t)(n0 + s) * D_DIM + d;
  const float* ap = addsrc ? addsrc + (size_t)(n0 + s) * D_DIM + d : nullptr;
  const char* hbase = (const char*)&h_lds[0][0] + lr * 528 + kg * 16;

  // distance-2 software pipeline on P (and addsrc)
  unsigned short c1 = Pp[0], c2 = Pp[256], c3 = Pp[512];
  unsigned short n1 = 0, n2 = 0, n3 = 0;
  {
    const unsigned short* Pn = Pp + (size_t)N_DIM * 768;
    n1 = Pn[0]; n2 = Pn[256]; n3 = Pn[512];
  }
  float av = ap ? ap[0] : 0.f;
  float nav = ap ? ap[(size_t)N_DIM * D_DIM] : 0.f;

  for (int t = 0; t < T_DIM; ++t) {
    // issue loads for t+2
    unsigned short m1 = 0, m2 = 0, m3 = 0;
    float mav = 0.f;
    if (t + 2 < T_DIM) {
      const unsigned short* Pm = Pp + (size_t)(t + 2) * N_DIM * 768;
      m1 = Pm[0]; m2 = Pm[256]; m3 = Pm[512];
      if (ap) mav = ap[(size_t)(t + 2) * N_DIM * D_DIM];
    }

    // MFMA phase: acc[SEQ seq][96-col slice] += h @ Wh^T
    f32x4 acc[6] = {};
#pragma unroll
    for (int kt = 0; kt < 8; ++kt) {
      const bf16x8 a = *(const bf16x8*)(hbase + kt * 64);
#pragma unroll
      for (int nt = 0; nt < 6; ++nt)
        acc[nt] = __builtin_amdgcn_mfma_f32_16x16x32_bf16(a, wreg[nt][kt], acc[nt], 0, 0, 0);
    }
    if (l < 16) {  // kg==0 lanes hold D rows 0..3; rows 0..SEQ-1 are valid
#pragma unroll
      for (int nt = 0; nt < 6; ++nt)
#pragma unroll
      for (int j = 0; j < SCAN_SEQ; ++j)
        acc_lds[j][w * 96 + nt * 16 + lr] = acc[nt][j];
    }
    __syncthreads();

    // combine: h_new = sig(gpre)*tanh(a1) + (1-sig)*tanh(a2)
    const float dt = dts[t];
    const float a1 = acc_lds[s][d] + bf_to_f(c1);
    const float a2 = acc_lds[s][256 + d] + bf_to_f(c2);
    const float a3 = acc_lds[s][512 + d] + bf_to_f(c3) - tau * dt;
    const float e1 = __expf(-2.f * fabsf(a1));
    const float f1 = copysignf((1.f - e1) / (1.f + e1), a1);
    const float e2 = __expf(-2.f * fabsf(a2));
    const float f2 = copysignf((1.f - e2) / (1.f + e2), a2);
    const float g = 1.f / (1.f + __expf(-a3));
    const float hn = g * f1 + (1.f - g) * f2;
    h_lds[s][d] = (__bf16)hn;
    op[(size_t)t * N_DIM * D_DIM] = hn + av;
    __syncthreads();

    c1 = n1; c2 = n2; c3 = n3; av = nav;
    n1 = m1; n2 = m2; n3 = m3; nav = mav;
  }
}

// ---------------- prep kernels ---------------------------------------------
__global__ void cvt_kernel(const float* __restrict__ src, __bf16* __restrict__ dst, int n) {
  const int i = blockIdx.x * 256 + threadIdx.x;
  if (i < n) dst[i] = (__bf16)src[i];
}

__global__ void pack_cell_kernel(const float* __restrict__ w1, const float* __restrict__ w2,
                                 const float* __restrict__ wt, __bf16* __restrict__ Wx,
                                 __bf16* __restrict__ Whb) {
  const int idx = blockIdx.x * 256 + threadIdx.x;  // over 3*768*256
  if (idx >= 3 * 768 * 256) return;
  const int l = idx / (768 * 256);
  const int r2 = idx - l * (768 * 256);
  const int jj = r2 >> 8;  // 0..767
  const int c = r2 & 255;
  const int m = jj >> 8;  // which matrix
  const int r = jj & 255;
  const float* src = (m == 0 ? w1 : (m == 1 ? w2 : wt)) + ((size_t)l * 256 + r) * 512;
  Wx[(size_t)l * (768 * 256) + (size_t)jj * 256 + c] = (__bf16)src[c];
  Whb[(size_t)l * (768 * 256) + (size_t)jj * 256 + c] = (__bf16)src[256 + c];
}

__global__ void bias_pack_kernel(const float* __restrict__ b1, const float* __restrict__ b2,
                                 const float* __restrict__ bt, const float* __restrict__ ff2b,
                                 const float* __restrict__ rw, const float* __restrict__ rb,
                                 const float* __restrict__ rn, float* __restrict__ bias768,
                                 float* __restrict__ ff2bias) {
  const int idx = blockIdx.x * 256 + threadIdx.x;
  if (idx < 3 * 768) {
    const int l = idx / 768, jj = idx % 768, m = jj >> 8, r = jj & 255;
    const float* s = (m == 0 ? b1 : (m == 1 ? b2 : bt));
    bias768[idx] = s[l * 256 + r];
  }
  if (idx < 256) ff2bias[idx] = ff2b[idx] + rw[idx] * rn[0] + rb[idx];
}

// ---------------------------------------------------------------------------
extern "C" void kernel_launch(void* const* d_in, const int* in_sizes, int n_in,
                              void* d_out, int out_size, void* d_ws, size_t ws_size,
                              hipStream_t stream) {
  (void)in_sizes; (void)n_in; (void)out_size; (void)ws_size;
  const float* spatial = (const float*)d_in[0];
  const float* re_norm = (const float*)d_in[1];
  const float* sensor_time = (const float*)d_in[2];
  const float* re_proj_w = (const float*)d_in[3];
  const float* re_proj_b = (const float*)d_in[4];
  const float* n1s = (const float*)d_in[5];
  const float* n1b = (const float*)d_in[6];
  const float* in_w = (const float*)d_in[7];
  const float* in_b = (const float*)d_in[8];
  const float* out_w = (const float*)d_in[9];
  const float* out_b = (const float*)d_in[10];
  const float* n2s = (const float*)d_in[11];
  const float* n2b = (const float*)d_in[12];
  const float* ff1_w = (const float*)d_in[13];
  const float* ff1_b = (const float*)d_in[14];
  const float* ff2_w = (const float*)d_in[15];
  const float* ff2_b = (const float*)d_in[16];
  const float* c1w = (const float*)d_in[17];
  const float* c1b = (const float*)d_in[18];
  const float* c2w = (const float*)d_in[19];
  const float* c2b = (const float*)d_in[20];
  const float* clt = (const float*)d_in[21];
  const float* ctw = (const float*)d_in[22];
  const float* ctb = (const float*)d_in[23];

  char* ws = (char*)d_ws;
  size_t off = 0;
  auto alloc = [&](size_t b) {
    char* p = ws + off;
    off = (off + b + 255) & ~(size_t)255;
    return p;
  };
  // persistent-per-layer buffers
  float* seq = (float*)alloc((size_t)TN * D_DIM * 4);      // 33.5 MB
  float* xb = (float*)alloc((size_t)TN * D_DIM * 4);       // 33.5 MB
  __bf16* yb = (__bf16*)alloc((size_t)TN * D_DIM * 2);     // 16.8 MB
  // big aliased region: qkv (bf16 TN*768) / ff1-out (bf16 TN*512) / P (bf16 TN*768)
  char* big = (char*)alloc((size_t)TN * 768 * 2);          // 50.3 MB
  __bf16* qkvb = (__bf16*)big;
  __bf16* gb = (__bf16*)big;
  __bf16* Pb = (__bf16*)big;
  // weights (~3.4 MB)
  __bf16* w_in = (__bf16*)alloc(768 * 256 * 2);
  __bf16* w_out = (__bf16*)alloc(256 * 256 * 2);
  __bf16* w_f1 = (__bf16*)alloc(512 * 256 * 2);
  __bf16* w_f2 = (__bf16*)alloc(256 * 512 * 2);
  __bf16* Wx = (__bf16*)alloc((size_t)3 * 768 * 256 * 2);
  __bf16* Whb = (__bf16*)alloc((size_t)3 * 768 * 256 * 2);
  float* b768 = (float*)alloc(3 * 768 * 4);
  float* f2bias = (float*)alloc(256 * 4);

  cvt_kernel<<<(768 * 256 + 255) / 256, 256, 0, stream>>>(in_w, w_in, 768 * 256);
  cvt_kernel<<<(256 * 256 + 255) / 256, 256, 0, stream>>>(out_w, w_out, 256 * 256);
  cvt_kernel<<<(512 * 256 + 255) / 256, 256, 0, stream>>>(ff1_w, w_f1, 512 * 256);
  cvt_kernel<<<(256 * 512 + 255) / 256, 256, 0, stream>>>(ff2_w, w_f2, 256 * 512);
  pack_cell_kernel<<<(3 * 768 * 256 + 255) / 256, 256, 0, stream>>>(c1w, c2w, ctw, Wx, Whb);
  bias_pack_kernel<<<9, 256, 0, stream>>>(c1b, c2b, ctb, ff2_b, re_proj_w, re_proj_b,
                                          re_norm, b768, f2bias);

  for (int l = 0; l < L_DIM; ++l) {
    const float* seq_in = (l == 0) ? spatial : seq;
    ln_kernel<<<TN / 4, 256, 0, stream>>>(seq_in, n1s, n1b, yb);
    gemm_kernel<0, 1><<<dim3(TN / 64, 768 / 64), 256, 0, stream>>>(yb, w_in, in_b, nullptr,
                                                                   qkvb, TN, 768, 256);
    attn_kernel<<<dim3(T_DIM, H_DIM), 256, 0, stream>>>(qkvb, yb);
    gemm_kernel<1, 0><<<dim3(TN / 64, 256 / 64), 256, 0, stream>>>(yb, w_out, out_b, seq_in,
                                                                   xb, TN, 256, 256);
    ln_kernel<<<TN / 4, 256, 0, stream>>>(xb, n2s, n2b, yb);
    gemm_kernel<2, 1><<<dim3(TN / 64, 512 / 64), 256, 0, stream>>>(yb, w_f1, ff1_b, nullptr,
                                                                   gb, TN, 512, 256);
    gemm_kernel<1, 1><<<dim3(TN / 64, 256 / 64), 256, 0, stream>>>(gb, w_f2, f2bias, xb, yb,
                                                                   TN, 256, 512);
    gemm_kernel<0, 1><<<dim3(TN / 64, 768 / 64), 256, 0, stream>>>(
        yb, Wx + (size_t)l * 768 * 256, b768 + l * 768, nullptr, Pb, TN, 768, 256);
    float* outp = (l == 2) ? (float*)d_out : seq;
    const float* addp = (l == 0) ? nullptr : seq;
    scan_mfma<<<N_DIM / SCAN_SEQ, 512, 0, stream>>>(Pb, Whb + (size_t)l * 768 * 256,
                                                    clt + l * 256, sensor_time, addp, outp);
  }
}

// Round 5
// 2177.134 us; speedup vs baseline: 2.3499x; 1.3094x over previous
//
#include <hip/hip_runtime.h>

// ---------------------------------------------------------------------------
// TemporalCfCEncoder: T=128, N=256, D=256, H=4 heads (hd=64), L=3 layers.
//  - token block batched over T*N rows, bf16 MFMA GEMMs
//  - attention: MFMA, S^T = K@Q^T (operands direct from global), softmax
//    in-register (per-lane column), O^T = V^T@P^T via XOR-swizzled LDS.
//  - CfC scan: x-part GEMM -> P; h-part MFMA scan, SEQ=2 seqs/WG, Wh
//    VGPR-resident, distance-2 P prefetch.
// ---------------------------------------------------------------------------

#define T_DIM 128
#define N_DIM 256
#define D_DIM 256
#define H_DIM 4
#define HD_DIM 64
#define L_DIM 3
#define TN (T_DIM * N_DIM)
#define SCAN_SEQ 2

typedef __bf16 bf16x8 __attribute__((ext_vector_type(8)));
typedef __bf16 bf16x4 __attribute__((ext_vector_type(4)));
typedef float f32x4 __attribute__((ext_vector_type(4)));

__device__ inline float wave_reduce_sum(float v) {
#pragma unroll
  for (int off = 32; off > 0; off >>= 1) v += __shfl_xor(v, off);
  return v;
}

__device__ inline float bf_to_f(unsigned short u) {
  return __uint_as_float((unsigned int)u << 16);
}

// ---------------- LN: one wave per row of 256, f32 in -> bf16 out ----------
__global__ __launch_bounds__(256) void ln_kernel(const float* __restrict__ x,
                                                 const float* __restrict__ sc,
                                                 const float* __restrict__ bi,
                                                 __bf16* __restrict__ y) {
  const int wid = threadIdx.x >> 6;
  const int lane = threadIdx.x & 63;
  const size_t row = (size_t)blockIdx.x * 4 + wid;
  const float4 xv = *(const float4*)(x + row * D_DIM + lane * 4);
  float s = xv.x + xv.y + xv.z + xv.w;
  float ss = xv.x * xv.x + xv.y * xv.y + xv.z * xv.z + xv.w * xv.w;
  s = wave_reduce_sum(s);
  ss = wave_reduce_sum(ss);
  const float mean = s * (1.f / D_DIM);
  const float var = ss * (1.f / D_DIM) - mean * mean;
  const float r = rsqrtf(var + 1e-5f);
  const float4 scv = *(const float4*)(sc + lane * 4);
  const float4 biv = *(const float4*)(bi + lane * 4);
  bf16x4 ov;
  ov[0] = (__bf16)((xv.x - mean) * r * scv.x + biv.x);
  ov[1] = (__bf16)((xv.y - mean) * r * scv.y + biv.y);
  ov[2] = (__bf16)((xv.z - mean) * r * scv.z + biv.z);
  ov[3] = (__bf16)((xv.w - mean) * r * scv.w + biv.w);
  *(bf16x4*)(y + row * D_DIM + lane * 4) = ov;
}

// ---------------- GEMM: out = A[M,K] @ W[Nout,K]^T + bias (+epilogue) ------
template <int EPI, int OBF>
__global__ __launch_bounds__(256) void gemm_kernel(const __bf16* __restrict__ A,
                                                   const __bf16* __restrict__ W,
                                                   const float* __restrict__ bias,
                                                   const float* __restrict__ R,
                                                   void* __restrict__ outv,
                                                   int M, int Nout, int K) {
  const int w = threadIdx.x >> 6;
  const int l = threadIdx.x & 63;
  const int lr = l & 15;   // A row / B col within 16-tile
  const int kg = l >> 4;   // k-group (8 elems each)
  const int m0 = blockIdx.x * 64 + w * 16;
  const int n0 = blockIdx.y * 64;
  const __bf16* Arow = A + (size_t)(m0 + lr) * K + kg * 8;
  f32x4 acc[4] = {};
  for (int k0 = 0; k0 < K; k0 += 32) {
    bf16x8 a = *(const bf16x8*)(Arow + k0);
#pragma unroll
    for (int nt = 0; nt < 4; ++nt) {
      bf16x8 b = *(const bf16x8*)(W + (size_t)(n0 + nt * 16 + lr) * K + kg * 8 + k0);
      acc[nt] = __builtin_amdgcn_mfma_f32_16x16x32_bf16(a, b, acc[nt], 0, 0, 0);
    }
  }
#pragma unroll
  for (int nt = 0; nt < 4; ++nt) {
    const int col = n0 + nt * 16 + lr;
    const float bv = bias[col];
#pragma unroll
    for (int j = 0; j < 4; ++j) {
      const int row = m0 + kg * 4 + j;
      float v = acc[nt][j] + bv;
      if (EPI == 1) v += R[(size_t)row * Nout + col];
      if (EPI == 2) v = v * (1.f / (1.f + __expf(-v)));
      const size_t oi = (size_t)row * Nout + col;
      if (OBF)
        ((__bf16*)outv)[oi] = (__bf16)v;
      else
        ((float*)outv)[oi] = v;
    }
  }
}

// ---------------- Attention (MFMA): one WG per (t, head), 4 waves ----------
// S^T = K @ Q^T (A,B direct from global); softmax per-lane (q = lr);
// O^T = V^T @ P^T with V_t and per-wave P in XOR-swizzled LDS.
__global__ __launch_bounds__(256, 2) void attn_mfma(const __bf16* __restrict__ qkv,
                                                    __bf16* __restrict__ o) {
  const int t = blockIdx.x, h = blockIdx.y;
  const int tid = threadIdx.x;
  const int w = tid >> 6, l = tid & 63;
  const int lr = l & 15, kg = l >> 4;

  __shared__ __bf16 vt_lds[64 * 256];    // V^T [c][n], XOR-swizzled, 32KB
  __shared__ __bf16 p_lds[4][16 * 256];  // per-wave P [q][n], swizzled, 32KB

  // ---- stage V^T: thread tid owns source row n = tid ----
  {
    const __bf16* vrow = qkv + ((size_t)(t * N_DIM + tid)) * 768 + 512 + h * HD_DIM;
#pragma unroll
    for (int c8 = 0; c8 < 64; c8 += 8) {
      bf16x8 v = *(const bf16x8*)(vrow + c8);
#pragma unroll
      for (int i = 0; i < 8; ++i) {
        const int c = c8 + i;
        const int byte = (c * 512 + tid * 2) ^ ((c & 7) << 4);
        *(__bf16*)((char*)vt_lds + byte) = v[i];
      }
    }
  }
  __syncthreads();

  const __bf16* kbase = qkv + (size_t)t * N_DIM * 768 + 256 + h * HD_DIM;
  const __bf16* qbase = qkv + (size_t)t * N_DIM * 768 + h * HD_DIM;
  char* pw = (char*)&p_lds[w][0];

  for (int qt = 0; qt < 4; ++qt) {
    const int q0 = w * 64 + qt * 16;
    // B-frags of Q^T: col=q0+lr, k contiguous
    const bf16x8 qf0 = *(const bf16x8*)(qbase + (size_t)(q0 + lr) * 768 + kg * 8);
    const bf16x8 qf1 = *(const bf16x8*)(qbase + (size_t)(q0 + lr) * 768 + 32 + kg * 8);
    // S^T = K @ Q^T : acc[nt][j] = S^T[nt*16+kg*4+j][q0+lr]
    f32x4 acc[16];
#pragma unroll
    for (int nt = 0; nt < 16; ++nt) {
      const bf16x8 a0 = *(const bf16x8*)(kbase + (size_t)(nt * 16 + lr) * 768 + kg * 8);
      const bf16x8 a1 = *(const bf16x8*)(kbase + (size_t)(nt * 16 + lr) * 768 + 32 + kg * 8);
      f32x4 s = {};
      s = __builtin_amdgcn_mfma_f32_16x16x32_bf16(a0, qf0, s, 0, 0, 0);
      s = __builtin_amdgcn_mfma_f32_16x16x32_bf16(a1, qf1, s, 0, 0, 0);
      acc[nt] = s;
    }
    // softmax over n for fixed q=lr: in-lane 64 + cross-kg shfl
    float mx = -3.0e38f;
#pragma unroll
    for (int nt = 0; nt < 16; ++nt)
#pragma unroll
      for (int j = 0; j < 4; ++j) mx = fmaxf(mx, acc[nt][j]);
    mx = fmaxf(mx, __shfl_xor(mx, 16));
    mx = fmaxf(mx, __shfl_xor(mx, 32));
    float sum = 0.f;
#pragma unroll
    for (int nt = 0; nt < 16; ++nt) {
      bf16x4 pb;
#pragma unroll
      for (int j = 0; j < 4; ++j) {
        const float p = __expf((acc[nt][j] - mx) * 0.125f);  // 1/sqrt(64)
        pb[j] = (__bf16)p;
        sum += (float)pb[j];  // sum the rounded values actually used in PV
      }
      const int byte = (lr * 512 + nt * 32 + kg * 8) ^ ((lr & 7) << 4);
      *(bf16x4*)(pw + byte) = pb;
    }
    sum += __shfl_xor(sum, 16);
    sum += __shfl_xor(sum, 32);
    const float inv = 1.f / sum;
    // O^T = V^T @ P^T : oacc[ct][j] = O^T[ct*16+kg*4+j][q0+lr]
    f32x4 oacc[4] = {};
#pragma unroll
    for (int kt = 0; kt < 8; ++kt) {
      const int pbyte = (lr * 512 + kt * 64 + kg * 16) ^ ((lr & 7) << 4);
      const bf16x8 bfrag = *(const bf16x8*)(pw + pbyte);
#pragma unroll
      for (int ct = 0; ct < 4; ++ct) {
        const int c = ct * 16 + lr;
        const int vbyte = (c * 512 + kt * 64 + kg * 16) ^ ((c & 7) << 4);
        const bf16x8 afrag = *(const bf16x8*)((char*)vt_lds + vbyte);
        oacc[ct] = __builtin_amdgcn_mfma_f32_16x16x32_bf16(afrag, bfrag, oacc[ct], 0, 0, 0);
      }
    }
    // epilogue: O[q0+lr][h*64 + ct*16 + kg*4 + j], j contiguous -> 8B stores
    __bf16* orow = o + ((size_t)(t * N_DIM + q0 + lr)) * D_DIM + h * HD_DIM;
#pragma unroll
    for (int ct = 0; ct < 4; ++ct) {
      bf16x4 ov;
#pragma unroll
      for (int j = 0; j < 4; ++j) ov[j] = (__bf16)(oacc[ct][j] * inv);
      *(bf16x4*)(orow + ct * 16 + kg * 4) = ov;
    }
  }
}

// ---------------- CfC scan (MFMA): SEQ=2 sequences/WG, Wh in VGPRs ---------
__global__ __launch_bounds__(512) void scan_mfma(const __bf16* __restrict__ P,
                                                 const __bf16* __restrict__ Wh,
                                                 const float* __restrict__ logtau,
                                                 const float* __restrict__ st,
                                                 const float* __restrict__ addsrc,
                                                 float* __restrict__ out) {
  const int tid = threadIdx.x;
  const int w = tid >> 6, l = tid & 63;
  const int lr = l & 15, kg = l >> 4;
  const int n0 = blockIdx.x * SCAN_SEQ;

  __shared__ float acc_lds[SCAN_SEQ][772];
  __shared__ __bf16 h_lds[16][264];  // 528B row stride; rows >= SEQ stay 0
  __shared__ float dts[T_DIM];

  if (tid < T_DIM) dts[tid] = (tid == 0) ? st[0] : st[tid] - st[tid - 1];
  for (int i = tid; i < 16 * 33; i += 512) ((bf16x8*)h_lds)[i] = (bf16x8){};

  bf16x8 wreg[6][8];
  {
    const __bf16* wb = Wh + (size_t)(w * 96 + lr) * 256 + kg * 8;
#pragma unroll
    for (int nt = 0; nt < 6; ++nt)
#pragma unroll
      for (int kt = 0; kt < 8; ++kt)
        wreg[nt][kt] = *(const bf16x8*)(wb + (size_t)nt * 16 * 256 + kt * 32);
  }
  __syncthreads();

  const int s = tid >> 8;    // 0..1
  const int d = tid & 255;   // 0..255
  const float tau = __expf(logtau[d]);
  const unsigned short* Pp = (const unsigned short*)P + (size_t)(n0 + s) * 768 + d;
  float* op = out + (size_t)(n0 + s) * D_DIM + d;
  const float* ap = addsrc ? addsrc + (size_t)(n0 + s) * D_DIM + d : nullptr;
  const char* hbase = (const char*)&h_lds[0][0] + lr * 528 + kg * 16;

  unsigned short c1 = Pp[0], c2 = Pp[256], c3 = Pp[512];
  unsigned short n1 = 0, n2 = 0, n3 = 0;
  {
    const unsigned short* Pn = Pp + (size_t)N_DIM * 768;
    n1 = Pn[0]; n2 = Pn[256]; n3 = Pn[512];
  }
  float av = ap ? ap[0] : 0.f;
  float nav = ap ? ap[(size_t)N_DIM * D_DIM] : 0.f;

  for (int t = 0; t < T_DIM; ++t) {
    unsigned short m1 = 0, m2 = 0, m3 = 0;
    float mav = 0.f;
    if (t + 2 < T_DIM) {
      const unsigned short* Pm = Pp + (size_t)(t + 2) * N_DIM * 768;
      m1 = Pm[0]; m2 = Pm[256]; m3 = Pm[512];
      if (ap) mav = ap[(size_t)(t + 2) * N_DIM * D_DIM];
    }

    f32x4 acc[6] = {};
#pragma unroll
    for (int kt = 0; kt < 8; ++kt) {
      const bf16x8 a = *(const bf16x8*)(hbase + kt * 64);
#pragma unroll
      for (int nt = 0; nt < 6; ++nt)
        acc[nt] = __builtin_amdgcn_mfma_f32_16x16x32_bf16(a, wreg[nt][kt], acc[nt], 0, 0, 0);
    }
    if (l < 16) {
#pragma unroll
      for (int nt = 0; nt < 6; ++nt)
#pragma unroll
      for (int j = 0; j < SCAN_SEQ; ++j)
        acc_lds[j][w * 96 + nt * 16 + lr] = acc[nt][j];
    }
    __syncthreads();

    const float dt = dts[t];
    const float a1 = acc_lds[s][d] + bf_to_f(c1);
    const float a2 = acc_lds[s][256 + d] + bf_to_f(c2);
    const float a3 = acc_lds[s][512 + d] + bf_to_f(c3) - tau * dt;
    const float e1 = __expf(-2.f * fabsf(a1));
    const float f1 = copysignf((1.f - e1) / (1.f + e1), a1);
    const float e2 = __expf(-2.f * fabsf(a2));
    const float f2 = copysignf((1.f - e2) / (1.f + e2), a2);
    const float g = 1.f / (1.f + __expf(-a3));
    const float hn = g * f1 + (1.f - g) * f2;
    h_lds[s][d] = (__bf16)hn;
    op[(size_t)t * N_DIM * D_DIM] = hn + av;
    __syncthreads();

    c1 = n1; c2 = n2; c3 = n3; av = nav;
    n1 = m1; n2 = m2; n3 = m3; nav = mav;
  }
}

// ---------------- prep kernels ---------------------------------------------
__global__ void cvt_kernel(const float* __restrict__ src, __bf16* __restrict__ dst, int n) {
  const int i = blockIdx.x * 256 + threadIdx.x;
  if (i < n) dst[i] = (__bf16)src[i];
}

__global__ void pack_cell_kernel(const float* __restrict__ w1, const float* __restrict__ w2,
                                 const float* __restrict__ wt, __bf16* __restrict__ Wx,
                                 __bf16* __restrict__ Whb) {
  const int idx = blockIdx.x * 256 + threadIdx.x;  // over 3*768*256
  if (idx >= 3 * 768 * 256) return;
  const int l = idx / (768 * 256);
  const int r2 = idx - l * (768 * 256);
  const int jj = r2 >> 8;  // 0..767
  const int c = r2 & 255;
  const int m = jj >> 8;  // which matrix
  const int r = jj & 255;
  const float* src = (m == 0 ? w1 : (m == 1 ? w2 : wt)) + ((size_t)l * 256 + r) * 512;
  Wx[(size_t)l * (768 * 256) + (size_t)jj * 256 + c] = (__bf16)src[c];
  Whb[(size_t)l * (768 * 256) + (size_t)jj * 256 + c] = (__bf16)src[256 + c];
}

__global__ void bias_pack_kernel(const float* __restrict__ b1, const float* __restrict__ b2,
                                 const float* __restrict__ bt, const float* __restrict__ ff2b,
                                 const float* __restrict__ rw, const float* __restrict__ rb,
                                 const float* __restrict__ rn, float* __restrict__ bias768,
                                 float* __restrict__ ff2bias) {
  const int idx = blockIdx.x * 256 + threadIdx.x;
  if (idx < 3 * 768) {
    const int l = idx / 768, jj = idx % 768, m = jj >> 8, r = jj & 255;
    const float* s = (m == 0 ? b1 : (m == 1 ? b2 : bt));
    bias768[idx] = s[l * 256 + r];
  }
  if (idx < 256) ff2bias[idx] = ff2b[idx] + rw[idx] * rn[0] + rb[idx];
}

// ---------------------------------------------------------------------------
extern "C" void kernel_launch(void* const* d_in, const int* in_sizes, int n_in,
                              void* d_out, int out_size, void* d_ws, size_t ws_size,
                              hipStream_t stream) {
  (void)in_sizes; (void)n_in; (void)out_size; (void)ws_size;
  const float* spatial = (const float*)d_in[0];
  const float* re_norm = (const float*)d_in[1];
  const float* sensor_time = (const float*)d_in[2];
  const float* re_proj_w = (const float*)d_in[3];
  const float* re_proj_b = (const float*)d_in[4];
  const float* n1s = (const float*)d_in[5];
  const float* n1b = (const float*)d_in[6];
  const float* in_w = (const float*)d_in[7];
  const float* in_b = (const float*)d_in[8];
  const float* out_w = (const float*)d_in[9];
  const float* out_b = (const float*)d_in[10];
  const float* n2s = (const float*)d_in[11];
  const float* n2b = (const float*)d_in[12];
  const float* ff1_w = (const float*)d_in[13];
  const float* ff1_b = (const float*)d_in[14];
  const float* ff2_w = (const float*)d_in[15];
  const float* ff2_b = (const float*)d_in[16];
  const float* c1w = (const float*)d_in[17];
  const float* c1b = (const float*)d_in[18];
  const float* c2w = (const float*)d_in[19];
  const float* c2b = (const float*)d_in[20];
  const float* clt = (const float*)d_in[21];
  const float* ctw = (const float*)d_in[22];
  const float* ctb = (const float*)d_in[23];

  char* ws = (char*)d_ws;
  size_t off = 0;
  auto alloc = [&](size_t b) {
    char* p = ws + off;
    off = (off + b + 255) & ~(size_t)255;
    return p;
  };
  // persistent-per-layer buffers
  float* seq = (float*)alloc((size_t)TN * D_DIM * 4);      // 33.5 MB
  float* xb = (float*)alloc((size_t)TN * D_DIM * 4);       // 33.5 MB
  __bf16* yb = (__bf16*)alloc((size_t)TN * D_DIM * 2);     // 16.8 MB
  // big aliased region: qkv / ff1-out / P (disjoint live ranges)
  char* big = (char*)alloc((size_t)TN * 768 * 2);          // 50.3 MB
  __bf16* qkvb = (__bf16*)big;
  __bf16* gb = (__bf16*)big;
  __bf16* Pb = (__bf16*)big;
  // weights (~3.4 MB)
  __bf16* w_in = (__bf16*)alloc(768 * 256 * 2);
  __bf16* w_out = (__bf16*)alloc(256 * 256 * 2);
  __bf16* w_f1 = (__bf16*)alloc(512 * 256 * 2);
  __bf16* w_f2 = (__bf16*)alloc(256 * 512 * 2);
  __bf16* Wx = (__bf16*)alloc((size_t)3 * 768 * 256 * 2);
  __bf16* Whb = (__bf16*)alloc((size_t)3 * 768 * 256 * 2);
  float* b768 = (float*)alloc(3 * 768 * 4);
  float* f2bias = (float*)alloc(256 * 4);

  cvt_kernel<<<(768 * 256 + 255) / 256, 256, 0, stream>>>(in_w, w_in, 768 * 256);
  cvt_kernel<<<(256 * 256 + 255) / 256, 256, 0, stream>>>(out_w, w_out, 256 * 256);
  cvt_kernel<<<(512 * 256 + 255) / 256, 256, 0, stream>>>(ff1_w, w_f1, 512 * 256);
  cvt_kernel<<<(256 * 512 + 255) / 256, 256, 0, stream>>>(ff2_w, w_f2, 256 * 512);
  pack_cell_kernel<<<(3 * 768 * 256 + 255) / 256, 256, 0, stream>>>(c1w, c2w, ctw, Wx, Whb);
  bias_pack_kernel<<<9, 256, 0, stream>>>(c1b, c2b, ctb, ff2_b, re_proj_w, re_proj_b,
                                          re_norm, b768, f2bias);

  for (int l = 0; l < L_DIM; ++l) {
    const float* seq_in = (l == 0) ? spatial : seq;
    ln_kernel<<<TN / 4, 256, 0, stream>>>(seq_in, n1s, n1b, yb);
    gemm_kernel<0, 1><<<dim3(TN / 64, 768 / 64), 256, 0, stream>>>(yb, w_in, in_b, nullptr,
                                                                   qkvb, TN, 768, 256);
    attn_mfma<<<dim3(T_DIM, H_DIM), 256, 0, stream>>>(qkvb, yb);
    gemm_kernel<1, 0><<<dim3(TN / 64, 256 / 64), 256, 0, stream>>>(yb, w_out, out_b, seq_in,
                                                                   xb, TN, 256, 256);
    ln_kernel<<<TN / 4, 256, 0, stream>>>(xb, n2s, n2b, yb);
    gemm_kernel<2, 1><<<dim3(TN / 64, 512 / 64), 256, 0, stream>>>(yb, w_f1, ff1_b, nullptr,
                                                                   gb, TN, 512, 256);
    gemm_kernel<1, 1><<<dim3(TN / 64, 256 / 64), 256, 0, stream>>>(gb, w_f2, f2bias, xb, yb,
                                                                   TN, 256, 512);
    gemm_kernel<0, 1><<<dim3(TN / 64, 768 / 64), 256, 0, stream>>>(
        yb, Wx + (size_t)l * 768 * 256, b768 + l * 768, nullptr, Pb, TN, 768, 256);
    float* outp = (l == 2) ? (float*)d_out : seq;
    const float* addp = (l == 0) ? nullptr : seq;
    scan_mfma<<<N_DIM / SCAN_SEQ, 512, 0, stream>>>(Pb, Whb + (size_t)l * 768 * 256,
                                                    clt + l * 256, sensor_time, addp, outp);
  }
}

// Round 6
// 1225.724 us; speedup vs baseline: 4.1739x; 1.7762x over previous
//
#include <hip/hip_runtime.h>

// ---------------------------------------------------------------------------
// TemporalCfCEncoder: T=128, N=256, D=256, H=4 heads (hd=64), L=3 layers.
//  - token block batched over T*N rows; GEMMs: 128x128 tile, LDS-staged BK=64
//  - attention: MFMA, S^T = K@Q^T direct from global; O^T = V^T@P^T swizzled LDS
//  - CfC scan: x-part GEMM -> P; h-part MFMA scan, SEQ=2/WG, Wh VGPR-resident,
//    h in broadcast-friendly [2][264] LDS, distance-2 P prefetch.
// ---------------------------------------------------------------------------

#define T_DIM 128
#define N_DIM 256
#define D_DIM 256
#define H_DIM 4
#define HD_DIM 64
#define L_DIM 3
#define TN (T_DIM * N_DIM)
#define SCAN_SEQ 2

typedef __bf16 bf16x8 __attribute__((ext_vector_type(8)));
typedef __bf16 bf16x4 __attribute__((ext_vector_type(4)));
typedef float f32x4 __attribute__((ext_vector_type(4)));

__device__ inline float wave_reduce_sum(float v) {
#pragma unroll
  for (int off = 32; off > 0; off >>= 1) v += __shfl_xor(v, off);
  return v;
}

__device__ inline float bf_to_f(unsigned short u) {
  return __uint_as_float((unsigned int)u << 16);
}

// ---------------- LN: one wave per row of 256, f32 in -> bf16 out ----------
__global__ __launch_bounds__(256) void ln_kernel(const float* __restrict__ x,
                                                 const float* __restrict__ sc,
                                                 const float* __restrict__ bi,
                                                 __bf16* __restrict__ y) {
  const int wid = threadIdx.x >> 6;
  const int lane = threadIdx.x & 63;
  const size_t row = (size_t)blockIdx.x * 4 + wid;
  const float4 xv = *(const float4*)(x + row * D_DIM + lane * 4);
  float s = xv.x + xv.y + xv.z + xv.w;
  float ss = xv.x * xv.x + xv.y * xv.y + xv.z * xv.z + xv.w * xv.w;
  s = wave_reduce_sum(s);
  ss = wave_reduce_sum(ss);
  const float mean = s * (1.f / D_DIM);
  const float var = ss * (1.f / D_DIM) - mean * mean;
  const float r = rsqrtf(var + 1e-5f);
  const float4 scv = *(const float4*)(sc + lane * 4);
  const float4 biv = *(const float4*)(bi + lane * 4);
  bf16x4 ov;
  ov[0] = (__bf16)((xv.x - mean) * r * scv.x + biv.x);
  ov[1] = (__bf16)((xv.y - mean) * r * scv.y + biv.y);
  ov[2] = (__bf16)((xv.z - mean) * r * scv.z + biv.z);
  ov[3] = (__bf16)((xv.w - mean) * r * scv.w + biv.w);
  *(bf16x4*)(y + row * D_DIM + lane * 4) = ov;
}

// ---------------- Tiled GEMM: out = A[M,K] @ W[Nout,K]^T + bias (+epi) -----
// 128x128 tile/WG, 4 waves (2x2), wave does 64x64 (4x4 16x16 accs), BK=64
// staged in LDS via reg path. Staging loads issued before the barrier so HBM
// latency overlaps the previous k-step's MFMAs.
// EPI: 0 = bias, 1 = bias + residual R[M,Nout] (f32), 2 = bias + SiLU
// OBF: 1 -> bf16 out, 0 -> f32 out
template <int EPI, int OBF>
__global__ __launch_bounds__(256) void gemm_tiled(const __bf16* __restrict__ A,
                                                  const __bf16* __restrict__ W,
                                                  const float* __restrict__ bias,
                                                  const float* __restrict__ R,
                                                  void* __restrict__ outv,
                                                  int M, int Nout, int K) {
  __shared__ __bf16 a_lds[128][72];
  __shared__ __bf16 b_lds[128][72];
  const int tid = threadIdx.x;
  const int w = tid >> 6, l = tid & 63;
  const int lr = l & 15, kg = l >> 4;
  const int wm = (w & 1) * 64, wn = (w >> 1) * 64;
  const int m0 = blockIdx.x * 128, n0 = blockIdx.y * 128;
  // staging map: thread -> (row = tid>>1, 32-col half = (tid&1)*32)
  const int srow = tid >> 1, scol = (tid & 1) * 32;
  const __bf16* ag = A + (size_t)(m0 + srow) * K + scol;
  const __bf16* bg = W + (size_t)(n0 + srow) * K + scol;

  f32x4 acc[4][4] = {};
  for (int k0 = 0; k0 < K; k0 += 64) {
    // issue staging loads (overlap previous compute)
    bf16x8 av[4], bv[4];
#pragma unroll
    for (int c = 0; c < 4; ++c) {
      av[c] = *(const bf16x8*)(ag + k0 + c * 8);
      bv[c] = *(const bf16x8*)(bg + k0 + c * 8);
    }
    __syncthreads();  // previous compute done reading LDS
#pragma unroll
    for (int c = 0; c < 4; ++c) {
      *(bf16x8*)&a_lds[srow][scol + c * 8] = av[c];
      *(bf16x8*)&b_lds[srow][scol + c * 8] = bv[c];
    }
    __syncthreads();  // staging visible
#pragma unroll
    for (int ks = 0; ks < 2; ++ks) {
      bf16x8 af[4], bf[4];
#pragma unroll
      for (int mt = 0; mt < 4; ++mt)
        af[mt] = *(const bf16x8*)&a_lds[wm + mt * 16 + lr][ks * 32 + kg * 8];
#pragma unroll
      for (int nt = 0; nt < 4; ++nt)
        bf[nt] = *(const bf16x8*)&b_lds[wn + nt * 16 + lr][ks * 32 + kg * 8];
#pragma unroll
      for (int mt = 0; mt < 4; ++mt)
#pragma unroll
        for (int nt = 0; nt < 4; ++nt)
          acc[mt][nt] =
              __builtin_amdgcn_mfma_f32_16x16x32_bf16(af[mt], bf[nt], acc[mt][nt], 0, 0, 0);
    }
  }
  // epilogue: D[row=kg*4+j][col=lr] per 16x16 tile
#pragma unroll
  for (int nt = 0; nt < 4; ++nt) {
    const int col = n0 + wn + nt * 16 + lr;
    const float bvs = bias[col];
#pragma unroll
    for (int mt = 0; mt < 4; ++mt) {
#pragma unroll
      for (int j = 0; j < 4; ++j) {
        const int row = m0 + wm + mt * 16 + kg * 4 + j;
        float v = acc[mt][nt][j] + bvs;
        if (EPI == 1) v += R[(size_t)row * Nout + col];
        if (EPI == 2) v = v * (1.f / (1.f + __expf(-v)));
        const size_t oi = (size_t)row * Nout + col;
        if (OBF)
          ((__bf16*)outv)[oi] = (__bf16)v;
        else
          ((float*)outv)[oi] = v;
      }
    }
  }
}

// ---------------- Attention (MFMA): one WG per (t, head), 4 waves ----------
__global__ __launch_bounds__(256, 2) void attn_mfma(const __bf16* __restrict__ qkv,
                                                    __bf16* __restrict__ o) {
  const int t = blockIdx.x, h = blockIdx.y;
  const int tid = threadIdx.x;
  const int w = tid >> 6, l = tid & 63;
  const int lr = l & 15, kg = l >> 4;

  __shared__ __bf16 vt_lds[64 * 256];    // V^T [c][n], XOR-swizzled, 32KB
  __shared__ __bf16 p_lds[4][16 * 256];  // per-wave P [q][n], swizzled, 32KB

  {
    const __bf16* vrow = qkv + ((size_t)(t * N_DIM + tid)) * 768 + 512 + h * HD_DIM;
#pragma unroll
    for (int c8 = 0; c8 < 64; c8 += 8) {
      bf16x8 v = *(const bf16x8*)(vrow + c8);
#pragma unroll
      for (int i = 0; i < 8; ++i) {
        const int c = c8 + i;
        const int byte = (c * 512 + tid * 2) ^ ((c & 7) << 4);
        *(__bf16*)((char*)vt_lds + byte) = v[i];
      }
    }
  }
  __syncthreads();

  const __bf16* kbase = qkv + (size_t)t * N_DIM * 768 + 256 + h * HD_DIM;
  const __bf16* qbase = qkv + (size_t)t * N_DIM * 768 + h * HD_DIM;
  char* pw = (char*)&p_lds[w][0];

  for (int qt = 0; qt < 4; ++qt) {
    const int q0 = w * 64 + qt * 16;
    const bf16x8 qf0 = *(const bf16x8*)(qbase + (size_t)(q0 + lr) * 768 + kg * 8);
    const bf16x8 qf1 = *(const bf16x8*)(qbase + (size_t)(q0 + lr) * 768 + 32 + kg * 8);
    f32x4 acc[16];
#pragma unroll
    for (int nt = 0; nt < 16; ++nt) {
      const bf16x8 a0 = *(const bf16x8*)(kbase + (size_t)(nt * 16 + lr) * 768 + kg * 8);
      const bf16x8 a1 = *(const bf16x8*)(kbase + (size_t)(nt * 16 + lr) * 768 + 32 + kg * 8);
      f32x4 s = {};
      s = __builtin_amdgcn_mfma_f32_16x16x32_bf16(a0, qf0, s, 0, 0, 0);
      s = __builtin_amdgcn_mfma_f32_16x16x32_bf16(a1, qf1, s, 0, 0, 0);
      acc[nt] = s;
    }
    float mx = -3.0e38f;
#pragma unroll
    for (int nt = 0; nt < 16; ++nt)
#pragma unroll
      for (int j = 0; j < 4; ++j) mx = fmaxf(mx, acc[nt][j]);
    mx = fmaxf(mx, __shfl_xor(mx, 16));
    mx = fmaxf(mx, __shfl_xor(mx, 32));
    float sum = 0.f;
#pragma unroll
    for (int nt = 0; nt < 16; ++nt) {
      bf16x4 pb;
#pragma unroll
      for (int j = 0; j < 4; ++j) {
        const float p = __expf((acc[nt][j] - mx) * 0.125f);
        pb[j] = (__bf16)p;
        sum += (float)pb[j];
      }
      const int byte = (lr * 512 + nt * 32 + kg * 8) ^ ((lr & 7) << 4);
      *(bf16x4*)(pw + byte) = pb;
    }
    sum += __shfl_xor(sum, 16);
    sum += __shfl_xor(sum, 32);
    const float inv = 1.f / sum;
    f32x4 oacc[4] = {};
#pragma unroll
    for (int kt = 0; kt < 8; ++kt) {
      const int pbyte = (lr * 512 + kt * 64 + kg * 16) ^ ((lr & 7) << 4);
      const bf16x8 bfrag = *(const bf16x8*)(pw + pbyte);
#pragma unroll
      for (int ct = 0; ct < 4; ++ct) {
        const int c = ct * 16 + lr;
        const int vbyte = (c * 512 + kt * 64 + kg * 16) ^ ((c & 7) << 4);
        const bf16x8 afrag = *(const bf16x8*)((char*)vt_lds + vbyte);
        oacc[ct] = __builtin_amdgcn_mfma_f32_16x16x32_bf16(afrag, bfrag, oacc[ct], 0, 0, 0);
      }
    }
    __bf16* orow = o + ((size_t)(t * N_DIM + q0 + lr)) * D_DIM + h * HD_DIM;
#pragma unroll
    for (int ct = 0; ct < 4; ++ct) {
      bf16x4 ov;
#pragma unroll
      for (int j = 0; j < 4; ++j) ov[j] = (__bf16)(oacc[ct][j] * inv);
      *(bf16x4*)(orow + ct * 16 + kg * 4) = ov;
    }
  }
}

// ---------------- CfC scan (MFMA): SEQ=2 sequences/WG, Wh in VGPRs ---------
// h stored [2][264]; every lane reads row (lr&1) -> 8 distinct 16B slots per
// read = LDS broadcast, ~no bank conflicts. D rows >=2 are garbage (never
// read: only j<SEQ written to acc_lds).
__global__ __launch_bounds__(512) void scan_mfma(const __bf16* __restrict__ P,
                                                 const __bf16* __restrict__ Wh,
                                                 const float* __restrict__ logtau,
                                                 const float* __restrict__ st,
                                                 const float* __restrict__ addsrc,
                                                 float* __restrict__ out) {
  const int tid = threadIdx.x;
  const int w = tid >> 6, l = tid & 63;
  const int lr = l & 15, kg = l >> 4;
  const int n0 = blockIdx.x * SCAN_SEQ;

  __shared__ float acc_lds[SCAN_SEQ][772];
  __shared__ __bf16 h_lds[2][264];  // 528B row stride
  __shared__ float dts[T_DIM];

  if (tid < T_DIM) dts[tid] = (tid == 0) ? st[0] : st[tid] - st[tid - 1];
  if (tid < 66) ((bf16x8*)h_lds)[tid] = (bf16x8){};

  bf16x8 wreg[6][8];
  {
    const __bf16* wb = Wh + (size_t)(w * 96 + lr) * 256 + kg * 8;
#pragma unroll
    for (int nt = 0; nt < 6; ++nt)
#pragma unroll
      for (int kt = 0; kt < 8; ++kt)
        wreg[nt][kt] = *(const bf16x8*)(wb + (size_t)nt * 16 * 256 + kt * 32);
  }
  __syncthreads();

  const int s = tid >> 8;    // 0..1
  const int d = tid & 255;   // 0..255
  const float tau = __expf(logtau[d]);
  const unsigned short* Pp = (const unsigned short*)P + (size_t)(n0 + s) * 768 + d;
  float* op = out + (size_t)(n0 + s) * D_DIM + d;
  const float* ap = addsrc ? addsrc + (size_t)(n0 + s) * D_DIM + d : nullptr;
  const char* hbase = (const char*)&h_lds[0][0] + (lr & 1) * 528 + kg * 16;

  unsigned short c1 = Pp[0], c2 = Pp[256], c3 = Pp[512];
  unsigned short n1 = 0, n2 = 0, n3 = 0;
  {
    const unsigned short* Pn = Pp + (size_t)N_DIM * 768;
    n1 = Pn[0]; n2 = Pn[256]; n3 = Pn[512];
  }
  float av = ap ? ap[0] : 0.f;
  float nav = ap ? ap[(size_t)N_DIM * D_DIM] : 0.f;

  for (int t = 0; t < T_DIM; ++t) {
    unsigned short m1 = 0, m2 = 0, m3 = 0;
    float mav = 0.f;
    if (t + 2 < T_DIM) {
      const unsigned short* Pm = Pp + (size_t)(t + 2) * N_DIM * 768;
      m1 = Pm[0]; m2 = Pm[256]; m3 = Pm[512];
      if (ap) mav = ap[(size_t)(t + 2) * N_DIM * D_DIM];
    }

    f32x4 acc[6] = {};
#pragma unroll
    for (int kt = 0; kt < 8; ++kt) {
      const bf16x8 a = *(const bf16x8*)(hbase + kt * 64);
#pragma unroll
      for (int nt = 0; nt < 6; ++nt)
        acc[nt] = __builtin_amdgcn_mfma_f32_16x16x32_bf16(a, wreg[nt][kt], acc[nt], 0, 0, 0);
    }
    if (l < 16) {  // kg==0 lanes hold D rows 0..3; rows 0..SEQ-1 valid
#pragma unroll
      for (int nt = 0; nt < 6; ++nt)
#pragma unroll
      for (int j = 0; j < SCAN_SEQ; ++j)
        acc_lds[j][w * 96 + nt * 16 + lr] = acc[nt][j];
    }
    __syncthreads();

    const float dt = dts[t];
    const float a1 = acc_lds[s][d] + bf_to_f(c1);
    const float a2 = acc_lds[s][256 + d] + bf_to_f(c2);
    const float a3 = acc_lds[s][512 + d] + bf_to_f(c3) - tau * dt;
    const float e1 = __expf(-2.f * fabsf(a1));
    const float f1 = copysignf((1.f - e1) / (1.f + e1), a1);
    const float e2 = __expf(-2.f * fabsf(a2));
    const float f2 = copysignf((1.f - e2) / (1.f + e2), a2);
    const float g = 1.f / (1.f + __expf(-a3));
    const float hn = g * f1 + (1.f - g) * f2;
    h_lds[s][d] = (__bf16)hn;
    op[(size_t)t * N_DIM * D_DIM] = hn + av;
    __syncthreads();

    c1 = n1; c2 = n2; c3 = n3; av = nav;
    n1 = m1; n2 = m2; n3 = m3; nav = mav;
  }
}

// ---------------- prep kernels ---------------------------------------------
__global__ void cvt_kernel(const float* __restrict__ src, __bf16* __restrict__ dst, int n) {
  const int i = blockIdx.x * 256 + threadIdx.x;
  if (i < n) dst[i] = (__bf16)src[i];
}

__global__ void pack_cell_kernel(const float* __restrict__ w1, const float* __restrict__ w2,
                                 const float* __restrict__ wt, __bf16* __restrict__ Wx,
                                 __bf16* __restrict__ Whb) {
  const int idx = blockIdx.x * 256 + threadIdx.x;  // over 3*768*256
  if (idx >= 3 * 768 * 256) return;
  const int l = idx / (768 * 256);
  const int r2 = idx - l * (768 * 256);
  const int jj = r2 >> 8;  // 0..767
  const int c = r2 & 255;
  const int m = jj >> 8;  // which matrix
  const int r = jj & 255;
  const float* src = (m == 0 ? w1 : (m == 1 ? w2 : wt)) + ((size_t)l * 256 + r) * 512;
  Wx[(size_t)l * (768 * 256) + (size_t)jj * 256 + c] = (__bf16)src[c];
  Whb[(size_t)l * (768 * 256) + (size_t)jj * 256 + c] = (__bf16)src[256 + c];
}

__global__ void bias_pack_kernel(const float* __restrict__ b1, const float* __restrict__ b2,
                                 const float* __restrict__ bt, const float* __restrict__ ff2b,
                                 const float* __restrict__ rw, const float* __restrict__ rb,
                                 const float* __restrict__ rn, float* __restrict__ bias768,
                                 float* __restrict__ ff2bias) {
  const int idx = blockIdx.x * 256 + threadIdx.x;
  if (idx < 3 * 768) {
    const int l = idx / 768, jj = idx % 768, m = jj >> 8, r = jj & 255;
    const float* s = (m == 0 ? b1 : (m == 1 ? b2 : bt));
    bias768[idx] = s[l * 256 + r];
  }
  if (idx < 256) ff2bias[idx] = ff2b[idx] + rw[idx] * rn[0] + rb[idx];
}

// ---------------------------------------------------------------------------
extern "C" void kernel_launch(void* const* d_in, const int* in_sizes, int n_in,
                              void* d_out, int out_size, void* d_ws, size_t ws_size,
                              hipStream_t stream) {
  (void)in_sizes; (void)n_in; (void)out_size; (void)ws_size;
  const float* spatial = (const float*)d_in[0];
  const float* re_norm = (const float*)d_in[1];
  const float* sensor_time = (const float*)d_in[2];
  const float* re_proj_w = (const float*)d_in[3];
  const float* re_proj_b = (const float*)d_in[4];
  const float* n1s = (const float*)d_in[5];
  const float* n1b = (const float*)d_in[6];
  const float* in_w = (const float*)d_in[7];
  const float* in_b = (const float*)d_in[8];
  const float* out_w = (const float*)d_in[9];
  const float* out_b = (const float*)d_in[10];
  const float* n2s = (const float*)d_in[11];
  const float* n2b = (const float*)d_in[12];
  const float* ff1_w = (const float*)d_in[13];
  const float* ff1_b = (const float*)d_in[14];
  const float* ff2_w = (const float*)d_in[15];
  const float* ff2_b = (const float*)d_in[16];
  const float* c1w = (const float*)d_in[17];
  const float* c1b = (const float*)d_in[18];
  const float* c2w = (const float*)d_in[19];
  const float* c2b = (const float*)d_in[20];
  const float* clt = (const float*)d_in[21];
  const float* ctw = (const float*)d_in[22];
  const float* ctb = (const float*)d_in[23];

  char* ws = (char*)d_ws;
  size_t off = 0;
  auto alloc = [&](size_t b) {
    char* p = ws + off;
    off = (off + b + 255) & ~(size_t)255;
    return p;
  };
  // persistent-per-layer buffers
  float* seq = (float*)alloc((size_t)TN * D_DIM * 4);      // 33.5 MB
  float* xb = (float*)alloc((size_t)TN * D_DIM * 4);       // 33.5 MB
  __bf16* yb = (__bf16*)alloc((size_t)TN * D_DIM * 2);     // 16.8 MB
  // big aliased region: qkv / ff1-out / P (disjoint live ranges)
  char* big = (char*)alloc((size_t)TN * 768 * 2);          // 50.3 MB
  __bf16* qkvb = (__bf16*)big;
  __bf16* gb = (__bf16*)big;
  __bf16* Pb = (__bf16*)big;
  // weights (~3.4 MB)
  __bf16* w_in = (__bf16*)alloc(768 * 256 * 2);
  __bf16* w_out = (__bf16*)alloc(256 * 256 * 2);
  __bf16* w_f1 = (__bf16*)alloc(512 * 256 * 2);
  __bf16* w_f2 = (__bf16*)alloc(256 * 512 * 2);
  __bf16* Wx = (__bf16*)alloc((size_t)3 * 768 * 256 * 2);
  __bf16* Whb = (__bf16*)alloc((size_t)3 * 768 * 256 * 2);
  float* b768 = (float*)alloc(3 * 768 * 4);
  float* f2bias = (float*)alloc(256 * 4);

  cvt_kernel<<<(768 * 256 + 255) / 256, 256, 0, stream>>>(in_w, w_in, 768 * 256);
  cvt_kernel<<<(256 * 256 + 255) / 256, 256, 0, stream>>>(out_w, w_out, 256 * 256);
  cvt_kernel<<<(512 * 256 + 255) / 256, 256, 0, stream>>>(ff1_w, w_f1, 512 * 256);
  cvt_kernel<<<(256 * 512 + 255) / 256, 256, 0, stream>>>(ff2_w, w_f2, 256 * 512);
  pack_cell_kernel<<<(3 * 768 * 256 + 255) / 256, 256, 0, stream>>>(c1w, c2w, ctw, Wx, Whb);
  bias_pack_kernel<<<9, 256, 0, stream>>>(c1b, c2b, ctb, ff2_b, re_proj_w, re_proj_b,
                                          re_norm, b768, f2bias);

  for (int l = 0; l < L_DIM; ++l) {
    const float* seq_in = (l == 0) ? spatial : seq;
    ln_kernel<<<TN / 4, 256, 0, stream>>>(seq_in, n1s, n1b, yb);
    gemm_tiled<0, 1><<<dim3(TN / 128, 768 / 128), 256, 0, stream>>>(yb, w_in, in_b, nullptr,
                                                                    qkvb, TN, 768, 256);
    attn_mfma<<<dim3(T_DIM, H_DIM), 256, 0, stream>>>(qkvb, yb);
    gemm_tiled<1, 0><<<dim3(TN / 128, 256 / 128), 256, 0, stream>>>(yb, w_out, out_b, seq_in,
                                                                    xb, TN, 256, 256);
    ln_kernel<<<TN / 4, 256, 0, stream>>>(xb, n2s, n2b, yb);
    gemm_tiled<2, 1><<<dim3(TN / 128, 512 / 128), 256, 0, stream>>>(yb, w_f1, ff1_b, nullptr,
                                                                    gb, TN, 512, 256);
    gemm_tiled<1, 1><<<dim3(TN / 128, 256 / 128), 256, 0, stream>>>(gb, w_f2, f2bias, xb, yb,
                                                                    TN, 256, 512);
    gemm_tiled<0, 1><<<dim3(TN / 128, 768 / 128), 256, 0, stream>>>(
        yb, Wx + (size_t)l * 768 * 256, b768 + l * 768, nullptr, Pb, TN, 768, 256);
    float* outp = (l == 2) ? (float*)d_out : seq;
    const float* addp = (l == 0) ? nullptr : seq;
    scan_mfma<<<N_DIM / SCAN_SEQ, 512, 0, stream>>>(Pb, Whb + (size_t)l * 768 * 256,
                                                    clt + l * 256, sensor_time, addp, outp);
  }
}

// Round 7
// 1202.928 us; speedup vs baseline: 4.2530x; 1.0190x over previous
//
#include <hip/hip_runtime.h>

// ---------------------------------------------------------------------------
// TemporalCfCEncoder: T=128, N=256, D=256, H=4 heads (hd=64), L=3 layers.
//  - token block batched over T*N rows; GEMMs: 128x128 tile, LDS-staged BK=64,
//    raw-barrier (lgkmcnt-only) k-loop with load-ahead so HBM staging flies
//    under the MFMA phase.
//  - attention: MFMA, S^T = K@Q^T direct from global; O^T = V^T@P^T swizzled LDS
//  - CfC scan: x-part GEMM -> P; h-part MFMA scan, SEQ=2/WG, Wh VGPR-resident,
//    raw barriers (no vmcnt drain) so the distance-2 P/addsrc prefetch
//    actually stays in flight across steps.
// ---------------------------------------------------------------------------

#define T_DIM 128
#define N_DIM 256
#define D_DIM 256
#define H_DIM 4
#define HD_DIM 64
#define L_DIM 3
#define TN (T_DIM * N_DIM)
#define SCAN_SEQ 2

typedef __bf16 bf16x8 __attribute__((ext_vector_type(8)));
typedef __bf16 bf16x4 __attribute__((ext_vector_type(4)));
typedef float f32x4 __attribute__((ext_vector_type(4)));

// LDS-only barrier: order ds ops across the WG without draining vmcnt, so
// global prefetch loads stay outstanding across steps (T4 pattern).
#define LDS_BAR()                                            \
  do {                                                       \
    asm volatile("s_waitcnt lgkmcnt(0)" ::: "memory");       \
    __builtin_amdgcn_s_barrier();                            \
    __builtin_amdgcn_sched_barrier(0);                       \
  } while (0)

__device__ inline float wave_reduce_sum(float v) {
#pragma unroll
  for (int off = 32; off > 0; off >>= 1) v += __shfl_xor(v, off);
  return v;
}

__device__ inline float bf_to_f(unsigned short u) {
  return __uint_as_float((unsigned int)u << 16);
}

// ---------------- LN: one wave per row of 256, f32 in -> bf16 out ----------
__global__ __launch_bounds__(256) void ln_kernel(const float* __restrict__ x,
                                                 const float* __restrict__ sc,
                                                 const float* __restrict__ bi,
                                                 __bf16* __restrict__ y) {
  const int wid = threadIdx.x >> 6;
  const int lane = threadIdx.x & 63;
  const size_t row = (size_t)blockIdx.x * 4 + wid;
  const float4 xv = *(const float4*)(x + row * D_DIM + lane * 4);
  float s = xv.x + xv.y + xv.z + xv.w;
  float ss = xv.x * xv.x + xv.y * xv.y + xv.z * xv.z + xv.w * xv.w;
  s = wave_reduce_sum(s);
  ss = wave_reduce_sum(ss);
  const float mean = s * (1.f / D_DIM);
  const float var = ss * (1.f / D_DIM) - mean * mean;
  const float r = rsqrtf(var + 1e-5f);
  const float4 scv = *(const float4*)(sc + lane * 4);
  const float4 biv = *(const float4*)(bi + lane * 4);
  bf16x4 ov;
  ov[0] = (__bf16)((xv.x - mean) * r * scv.x + biv.x);
  ov[1] = (__bf16)((xv.y - mean) * r * scv.y + biv.y);
  ov[2] = (__bf16)((xv.z - mean) * r * scv.z + biv.z);
  ov[3] = (__bf16)((xv.w - mean) * r * scv.w + biv.w);
  *(bf16x4*)(y + row * D_DIM + lane * 4) = ov;
}

// ---------------- Tiled GEMM: out = A[M,K] @ W[Nout,K]^T + bias (+epi) -----
// 128x128 tile/WG, 4 waves (2x2), wave does 64x64, BK=64 LDS-staged.
// Load-ahead: ds_write current k regs, issue k+1 global loads, raw barrier,
// MFMA -> k+1 loads in flight during the MFMA phase (no vmcnt drain).
template <int EPI, int OBF>
__global__ __launch_bounds__(256) void gemm_tiled(const __bf16* __restrict__ A,
                                                  const __bf16* __restrict__ W,
                                                  const float* __restrict__ bias,
                                                  const float* __restrict__ R,
                                                  void* __restrict__ outv,
                                                  int M, int Nout, int K) {
  __shared__ __bf16 a_lds[128][72];
  __shared__ __bf16 b_lds[128][72];
  const int tid = threadIdx.x;
  const int w = tid >> 6, l = tid & 63;
  const int lr = l & 15, kg = l >> 4;
  const int wm = (w & 1) * 64, wn = (w >> 1) * 64;
  const int m0 = blockIdx.x * 128, n0 = blockIdx.y * 128;
  const int srow = tid >> 1, scol = (tid & 1) * 32;
  const __bf16* ag = A + (size_t)(m0 + srow) * K + scol;
  const __bf16* bg = W + (size_t)(n0 + srow) * K + scol;

  bf16x8 av[4], bv[4];
#pragma unroll
  for (int c = 0; c < 4; ++c) {
    av[c] = *(const bf16x8*)(ag + c * 8);
    bv[c] = *(const bf16x8*)(bg + c * 8);
  }

  f32x4 acc[4][4] = {};
  for (int k0 = 0; k0 < K; k0 += 64) {
    LDS_BAR();  // all waves finished reading LDS of previous k-step
#pragma unroll
    for (int c = 0; c < 4; ++c) {
      *(bf16x8*)&a_lds[srow][scol + c * 8] = av[c];
      *(bf16x8*)&b_lds[srow][scol + c * 8] = bv[c];
    }
    if (k0 + 64 < K) {
#pragma unroll
      for (int c = 0; c < 4; ++c) {
        av[c] = *(const bf16x8*)(ag + k0 + 64 + c * 8);
        bv[c] = *(const bf16x8*)(bg + k0 + 64 + c * 8);
      }
    }
    LDS_BAR();  // staging visible; k+1 loads remain in flight
#pragma unroll
    for (int ks = 0; ks < 2; ++ks) {
      bf16x8 af[4], bf[4];
#pragma unroll
      for (int mt = 0; mt < 4; ++mt)
        af[mt] = *(const bf16x8*)&a_lds[wm + mt * 16 + lr][ks * 32 + kg * 8];
#pragma unroll
      for (int nt = 0; nt < 4; ++nt)
        bf[nt] = *(const bf16x8*)&b_lds[wn + nt * 16 + lr][ks * 32 + kg * 8];
#pragma unroll
      for (int mt = 0; mt < 4; ++mt)
#pragma unroll
        for (int nt = 0; nt < 4; ++nt)
          acc[mt][nt] =
              __builtin_amdgcn_mfma_f32_16x16x32_bf16(af[mt], bf[nt], acc[mt][nt], 0, 0, 0);
    }
  }
  // epilogue: D[row=kg*4+j][col=lr] per 16x16 tile
#pragma unroll
  for (int nt = 0; nt < 4; ++nt) {
    const int col = n0 + wn + nt * 16 + lr;
    const float bvs = bias[col];
#pragma unroll
    for (int mt = 0; mt < 4; ++mt) {
#pragma unroll
      for (int j = 0; j < 4; ++j) {
        const int row = m0 + wm + mt * 16 + kg * 4 + j;
        float v = acc[mt][nt][j] + bvs;
        if (EPI == 1) v += R[(size_t)row * Nout + col];
        if (EPI == 2) v = v * (1.f / (1.f + __expf(-v)));
        const size_t oi = (size_t)row * Nout + col;
        if (OBF)
          ((__bf16*)outv)[oi] = (__bf16)v;
        else
          ((float*)outv)[oi] = v;
      }
    }
  }
}

// ---------------- Attention (MFMA): one WG per (t, head), 4 waves ----------
__global__ __launch_bounds__(256, 2) void attn_mfma(const __bf16* __restrict__ qkv,
                                                    __bf16* __restrict__ o) {
  const int t = blockIdx.x, h = blockIdx.y;
  const int tid = threadIdx.x;
  const int w = tid >> 6, l = tid & 63;
  const int lr = l & 15, kg = l >> 4;

  __shared__ __bf16 vt_lds[64 * 256];    // V^T [c][n], XOR-swizzled, 32KB
  __shared__ __bf16 p_lds[4][16 * 256];  // per-wave P [q][n], swizzled, 32KB

  {
    const __bf16* vrow = qkv + ((size_t)(t * N_DIM + tid)) * 768 + 512 + h * HD_DIM;
#pragma unroll
    for (int c8 = 0; c8 < 64; c8 += 8) {
      bf16x8 v = *(const bf16x8*)(vrow + c8);
#pragma unroll
      for (int i = 0; i < 8; ++i) {
        const int c = c8 + i;
        const int byte = (c * 512 + tid * 2) ^ ((c & 7) << 4);
        *(__bf16*)((char*)vt_lds + byte) = v[i];
      }
    }
  }
  __syncthreads();

  const __bf16* kbase = qkv + (size_t)t * N_DIM * 768 + 256 + h * HD_DIM;
  const __bf16* qbase = qkv + (size_t)t * N_DIM * 768 + h * HD_DIM;
  char* pw = (char*)&p_lds[w][0];

  for (int qt = 0; qt < 4; ++qt) {
    const int q0 = w * 64 + qt * 16;
    const bf16x8 qf0 = *(const bf16x8*)(qbase + (size_t)(q0 + lr) * 768 + kg * 8);
    const bf16x8 qf1 = *(const bf16x8*)(qbase + (size_t)(q0 + lr) * 768 + 32 + kg * 8);
    f32x4 acc[16];
#pragma unroll
    for (int nt = 0; nt < 16; ++nt) {
      const bf16x8 a0 = *(const bf16x8*)(kbase + (size_t)(nt * 16 + lr) * 768 + kg * 8);
      const bf16x8 a1 = *(const bf16x8*)(kbase + (size_t)(nt * 16 + lr) * 768 + 32 + kg * 8);
      f32x4 s = {};
      s = __builtin_amdgcn_mfma_f32_16x16x32_bf16(a0, qf0, s, 0, 0, 0);
      s = __builtin_amdgcn_mfma_f32_16x16x32_bf16(a1, qf1, s, 0, 0, 0);
      acc[nt] = s;
    }
    float mx = -3.0e38f;
#pragma unroll
    for (int nt = 0; nt < 16; ++nt)
#pragma unroll
      for (int j = 0; j < 4; ++j) mx = fmaxf(mx, acc[nt][j]);
    mx = fmaxf(mx, __shfl_xor(mx, 16));
    mx = fmaxf(mx, __shfl_xor(mx, 32));
    float sum = 0.f;
#pragma unroll
    for (int nt = 0; nt < 16; ++nt) {
      bf16x4 pb;
#pragma unroll
      for (int j = 0; j < 4; ++j) {
        const float p = __expf((acc[nt][j] - mx) * 0.125f);
        pb[j] = (__bf16)p;
        sum += (float)pb[j];
      }
      const int byte = (lr * 512 + nt * 32 + kg * 8) ^ ((lr & 7) << 4);
      *(bf16x4*)(pw + byte) = pb;
    }
    sum += __shfl_xor(sum, 16);
    sum += __shfl_xor(sum, 32);
    const float inv = 1.f / sum;
    f32x4 oacc[4] = {};
#pragma unroll
    for (int kt = 0; kt < 8; ++kt) {
      const int pbyte = (lr * 512 + kt * 64 + kg * 16) ^ ((lr & 7) << 4);
      const bf16x8 bfrag = *(const bf16x8*)(pw + pbyte);
#pragma unroll
      for (int ct = 0; ct < 4; ++ct) {
        const int c = ct * 16 + lr;
        const int vbyte = (c * 512 + kt * 64 + kg * 16) ^ ((c & 7) << 4);
        const bf16x8 afrag = *(const bf16x8*)((char*)vt_lds + vbyte);
        oacc[ct] = __builtin_amdgcn_mfma_f32_16x16x32_bf16(afrag, bfrag, oacc[ct], 0, 0, 0);
      }
    }
    __bf16* orow = o + ((size_t)(t * N_DIM + q0 + lr)) * D_DIM + h * HD_DIM;
#pragma unroll
    for (int ct = 0; ct < 4; ++ct) {
      bf16x4 ov;
#pragma unroll
      for (int j = 0; j < 4; ++j) ov[j] = (__bf16)(oacc[ct][j] * inv);
      *(bf16x4*)(orow + ct * 16 + kg * 4) = ov;
    }
  }
}

// ---------------- CfC scan (MFMA): SEQ=2 sequences/WG, Wh in VGPRs ---------
// Raw LDS-only barriers: the distance-2 P/addsrc prefetch stays in flight
// across step barriers (no vmcnt(0) drain per step).
__global__ __launch_bounds__(512) void scan_mfma(const __bf16* __restrict__ P,
                                                 const __bf16* __restrict__ Wh,
                                                 const float* __restrict__ logtau,
                                                 const float* __restrict__ st,
                                                 const float* __restrict__ addsrc,
                                                 float* __restrict__ out) {
  const int tid = threadIdx.x;
  const int w = tid >> 6, l = tid & 63;
  const int lr = l & 15, kg = l >> 4;
  const int n0 = blockIdx.x * SCAN_SEQ;

  __shared__ float acc_lds[SCAN_SEQ][772];
  __shared__ __bf16 h_lds[2][264];  // 528B row stride
  __shared__ float dts[T_DIM];

  if (tid < T_DIM) dts[tid] = (tid == 0) ? st[0] : st[tid] - st[tid - 1];
  if (tid < 66) ((bf16x8*)h_lds)[tid] = (bf16x8){};

  bf16x8 wreg[6][8];
  {
    const __bf16* wb = Wh + (size_t)(w * 96 + lr) * 256 + kg * 8;
#pragma unroll
    for (int nt = 0; nt < 6; ++nt)
#pragma unroll
      for (int kt = 0; kt < 8; ++kt)
        wreg[nt][kt] = *(const bf16x8*)(wb + (size_t)nt * 16 * 256 + kt * 32);
  }
  __syncthreads();

  const int s = tid >> 8;    // 0..1
  const int d = tid & 255;   // 0..255
  const float tau = __expf(logtau[d]);
  const unsigned short* Pp = (const unsigned short*)P + (size_t)(n0 + s) * 768 + d;
  float* op = out + (size_t)(n0 + s) * D_DIM + d;
  const float* ap = addsrc ? addsrc + (size_t)(n0 + s) * D_DIM + d : nullptr;
  const char* hbase = (const char*)&h_lds[0][0] + (lr & 1) * 528 + kg * 16;

  unsigned short c1 = Pp[0], c2 = Pp[256], c3 = Pp[512];
  unsigned short n1 = 0, n2 = 0, n3 = 0;
  {
    const unsigned short* Pn = Pp + (size_t)N_DIM * 768;
    n1 = Pn[0]; n2 = Pn[256]; n3 = Pn[512];
  }
  float av = ap ? ap[0] : 0.f;
  float nav = ap ? ap[(size_t)N_DIM * D_DIM] : 0.f;

  for (int t = 0; t < T_DIM; ++t) {
    // issue loads for t+2; they stay in flight across the raw barriers
    unsigned short m1 = 0, m2 = 0, m3 = 0;
    float mav = 0.f;
    if (t + 2 < T_DIM) {
      const unsigned short* Pm = Pp + (size_t)(t + 2) * N_DIM * 768;
      m1 = Pm[0]; m2 = Pm[256]; m3 = Pm[512];
      if (ap) mav = ap[(size_t)(t + 2) * N_DIM * D_DIM];
    }

    f32x4 acc[6] = {};
#pragma unroll
    for (int kt = 0; kt < 8; ++kt) {
      const bf16x8 a = *(const bf16x8*)(hbase + kt * 64);
#pragma unroll
      for (int nt = 0; nt < 6; ++nt)
        acc[nt] = __builtin_amdgcn_mfma_f32_16x16x32_bf16(a, wreg[nt][kt], acc[nt], 0, 0, 0);
    }
    if (l < 16) {  // kg==0 lanes hold D rows 0..3; rows 0..SEQ-1 valid
#pragma unroll
      for (int nt = 0; nt < 6; ++nt)
#pragma unroll
      for (int j = 0; j < SCAN_SEQ; ++j)
        acc_lds[j][w * 96 + nt * 16 + lr] = acc[nt][j];
    }
    LDS_BAR();  // acc visible; h_lds reads of this step done

    const float dt = dts[t];
    const float a1 = acc_lds[s][d] + bf_to_f(c1);
    const float a2 = acc_lds[s][256 + d] + bf_to_f(c2);
    const float a3 = acc_lds[s][512 + d] + bf_to_f(c3) - tau * dt;
    const float e1 = __expf(-2.f * fabsf(a1));
    const float f1 = copysignf((1.f - e1) / (1.f + e1), a1);
    const float e2 = __expf(-2.f * fabsf(a2));
    const float f2 = copysignf((1.f - e2) / (1.f + e2), a2);
    const float g = 1.f / (1.f + __expf(-a3));
    const float hn = g * f1 + (1.f - g) * f2;
    h_lds[s][d] = (__bf16)hn;
    op[(size_t)t * N_DIM * D_DIM] = hn + av;
    LDS_BAR();  // h_new visible for next step's MFMA

    c1 = n1; c2 = n2; c3 = n3; av = nav;
    n1 = m1; n2 = m2; n3 = m3; nav = mav;
  }
}

// ---------------- prep kernels ---------------------------------------------
__global__ void cvt_kernel(const float* __restrict__ src, __bf16* __restrict__ dst, int n) {
  const int i = blockIdx.x * 256 + threadIdx.x;
  if (i < n) dst[i] = (__bf16)src[i];
}

__global__ void pack_cell_kernel(const float* __restrict__ w1, const float* __restrict__ w2,
                                 const float* __restrict__ wt, __bf16* __restrict__ Wx,
                                 __bf16* __restrict__ Whb) {
  const int idx = blockIdx.x * 256 + threadIdx.x;  // over 3*768*256
  if (idx >= 3 * 768 * 256) return;
  const int l = idx / (768 * 256);
  const int r2 = idx - l * (768 * 256);
  const int jj = r2 >> 8;  // 0..767
  const int c = r2 & 255;
  const int m = jj >> 8;  // which matrix
  const int r = jj & 255;
  const float* src = (m == 0 ? w1 : (m == 1 ? w2 : wt)) + ((size_t)l * 256 + r) * 512;
  Wx[(size_t)l * (768 * 256) + (size_t)jj * 256 + c] = (__bf16)src[c];
  Whb[(size_t)l * (768 * 256) + (size_t)jj * 256 + c] = (__bf16)src[256 + c];
}

__global__ void bias_pack_kernel(const float* __restrict__ b1, const float* __restrict__ b2,
                                 const float* __restrict__ bt, const float* __restrict__ ff2b,
                                 const float* __restrict__ rw, const float* __restrict__ rb,
                                 const float* __restrict__ rn, float* __restrict__ bias768,
                                 float* __restrict__ ff2bias) {
  const int idx = blockIdx.x * 256 + threadIdx.x;
  if (idx < 3 * 768) {
    const int l = idx / 768, jj = idx % 768, m = jj >> 8, r = jj & 255;
    const float* s = (m == 0 ? b1 : (m == 1 ? b2 : bt));
    bias768[idx] = s[l * 256 + r];
  }
  if (idx < 256) ff2bias[idx] = ff2b[idx] + rw[idx] * rn[0] + rb[idx];
}

// ---------------------------------------------------------------------------
extern "C" void kernel_launch(void* const* d_in, const int* in_sizes, int n_in,
                              void* d_out, int out_size, void* d_ws, size_t ws_size,
                              hipStream_t stream) {
  (void)in_sizes; (void)n_in; (void)out_size; (void)ws_size;
  const float* spatial = (const float*)d_in[0];
  const float* re_norm = (const float*)d_in[1];
  const float* sensor_time = (const float*)d_in[2];
  const float* re_proj_w = (const float*)d_in[3];
  const float* re_proj_b = (const float*)d_in[4];
  const float* n1s = (const float*)d_in[5];
  const float* n1b = (const float*)d_in[6];
  const float* in_w = (const float*)d_in[7];
  const float* in_b = (const float*)d_in[8];
  const float* out_w = (const float*)d_in[9];
  const float* out_b = (const float*)d_in[10];
  const float* n2s = (const float*)d_in[11];
  const float* n2b = (const float*)d_in[12];
  const float* ff1_w = (const float*)d_in[13];
  const float* ff1_b = (const float*)d_in[14];
  const float* ff2_w = (const float*)d_in[15];
  const float* ff2_b = (const float*)d_in[16];
  const float* c1w = (const float*)d_in[17];
  const float* c1b = (const float*)d_in[18];
  const float* c2w = (const float*)d_in[19];
  const float* c2b = (const float*)d_in[20];
  const float* clt = (const float*)d_in[21];
  const float* ctw = (const float*)d_in[22];
  const float* ctb = (const float*)d_in[23];

  char* ws = (char*)d_ws;
  size_t off = 0;
  auto alloc = [&](size_t b) {
    char* p = ws + off;
    off = (off + b + 255) & ~(size_t)255;
    return p;
  };
  // persistent-per-layer buffers
  float* seq = (float*)alloc((size_t)TN * D_DIM * 4);      // 33.5 MB
  float* xb = (float*)alloc((size_t)TN * D_DIM * 4);       // 33.5 MB
  __bf16* yb = (__bf16*)alloc((size_t)TN * D_DIM * 2);     // 16.8 MB
  // big aliased region: qkv / ff1-out / P (disjoint live ranges)
  char* big = (char*)alloc((size_t)TN * 768 * 2);          // 50.3 MB
  __bf16* qkvb = (__bf16*)big;
  __bf16* gb = (__bf16*)big;
  __bf16* Pb = (__bf16*)big;
  // weights (~3.4 MB)
  __bf16* w_in = (__bf16*)alloc(768 * 256 * 2);
  __bf16* w_out = (__bf16*)alloc(256 * 256 * 2);
  __bf16* w_f1 = (__bf16*)alloc(512 * 256 * 2);
  __bf16* w_f2 = (__bf16*)alloc(256 * 512 * 2);
  __bf16* Wx = (__bf16*)alloc((size_t)3 * 768 * 256 * 2);
  __bf16* Whb = (__bf16*)alloc((size_t)3 * 768 * 256 * 2);
  float* b768 = (float*)alloc(3 * 768 * 4);
  float* f2bias = (float*)alloc(256 * 4);

  cvt_kernel<<<(768 * 256 + 255) / 256, 256, 0, stream>>>(in_w, w_in, 768 * 256);
  cvt_kernel<<<(256 * 256 + 255) / 256, 256, 0, stream>>>(out_w, w_out, 256 * 256);
  cvt_kernel<<<(512 * 256 + 255) / 256, 256, 0, stream>>>(ff1_w, w_f1, 512 * 256);
  cvt_kernel<<<(256 * 512 + 255) / 256, 256, 0, stream>>>(ff2_w, w_f2, 256 * 512);
  pack_cell_kernel<<<(3 * 768 * 256 + 255) / 256, 256, 0, stream>>>(c1w, c2w, ctw, Wx, Whb);
  bias_pack_kernel<<<9, 256, 0, stream>>>(c1b, c2b, ctb, ff2_b, re_proj_w, re_proj_b,
                                          re_norm, b768, f2bias);

  for (int l = 0; l < L_DIM; ++l) {
    const float* seq_in = (l == 0) ? spatial : seq;
    ln_kernel<<<TN / 4, 256, 0, stream>>>(seq_in, n1s, n1b, yb);
    gemm_tiled<0, 1><<<dim3(TN / 128, 768 / 128), 256, 0, stream>>>(yb, w_in, in_b, nullptr,
                                                                    qkvb, TN, 768, 256);
    attn_mfma<<<dim3(T_DIM, H_DIM), 256, 0, stream>>>(qkvb, yb);
    gemm_tiled<1, 0><<<dim3(TN / 128, 256 / 128), 256, 0, stream>>>(yb, w_out, out_b, seq_in,
                                                                    xb, TN, 256, 256);
    ln_kernel<<<TN / 4, 256, 0, stream>>>(xb, n2s, n2b, yb);
    gemm_tiled<2, 1><<<dim3(TN / 128, 512 / 128), 256, 0, stream>>>(yb, w_f1, ff1_b, nullptr,
                                                                    gb, TN, 512, 256);
    gemm_tiled<1, 1><<<dim3(TN / 128, 256 / 128), 256, 0, stream>>>(gb, w_f2, f2bias, xb, yb,
                                                                    TN, 256, 512);
    gemm_tiled<0, 1><<<dim3(TN / 128, 768 / 128), 256, 0, stream>>>(
        yb, Wx + (size_t)l * 768 * 256, b768 + l * 768, nullptr, Pb, TN, 768, 256);
    float* outp = (l == 2) ? (float*)d_out : seq;
    const float* addp = (l == 0) ? nullptr : seq;
    scan_mfma<<<N_DIM / SCAN_SEQ, 512, 0, stream>>>(Pb, Whb + (size_t)l * 768 * 256,
                                                    clt + l * 256, sensor_time, addp, outp);
  }
}